// Round 1
// baseline (665.664 us; speedup 1.0000x reference)
//
#include <hip/hip_runtime.h>

constexpr int CN = 4;          // batch
constexpr int CC = 64;         // channels per window
constexpr int CH = 72, CW = 72;
constexpr int HW = CH * CW;    // 5184
constexpr int NPOS = CN * HW;  // 20736 positions total (= tokens per window)
constexpr long TOKF = 3L * NPOS * 64;  // floats in one [3][NPOS][64] array

// ---------------------------------------------------------------------------
// Kernel 0: transpose wq/wk/wv (64x64 each, [c][c'] -> [c'][c]) into ws
// ---------------------------------------------------------------------------
__global__ __launch_bounds__(256) void k_wT(const float* __restrict__ wq,
                                            const float* __restrict__ wk,
                                            const float* __restrict__ wv,
                                            float* __restrict__ wT) {
  int i = blockIdx.x * 256 + threadIdx.x;  // [0, 3*4096)
  int m = i >> 12;
  int r = i & 4095;
  int cp = r >> 6, c = r & 63;
  const float* src = (m == 0) ? wq : ((m == 1) ? wk : wv);
  wT[i] = src[c * 64 + cp];
}

// ---------------------------------------------------------------------------
// Kernel 1: expand conv (64 -> 64 for one window) + scatter to token order.
// thread = one position. ex_tok layout: [NPOS][64] token-major (per window).
// ---------------------------------------------------------------------------
template <int WW, int SS>
__global__ __launch_bounds__(256) void k_expand(const float* __restrict__ x,
                                                const float* __restrict__ w64,
                                                const float* __restrict__ b64,
                                                float* __restrict__ out) {
  int pg = blockIdx.x * 256 + threadIdx.x;  // [0, NPOS)
  int n = pg / HW;
  int pos = pg - n * HW;
  int h = pos / CW, wcol = pos % CW;

  float xv[64];
  const float* xp = x + (long)n * CC * HW + pos;
#pragma unroll
  for (int c = 0; c < 64; ++c) xv[c] = xp[c * HW];

  int wr = h / SS, kx = h % SS, wcq = wcol / SS, ky = wcol % SS;
  int j = kx * (SS * WW * WW) + ky * (WW * WW) + wr * WW + wcq;
  float* op = out + ((long)n * HW + j) * 64;

#pragma unroll 1
  for (int og = 0; og < 16; ++og) {
    float t0[4];
#pragma unroll
    for (int i = 0; i < 4; ++i) {
      int o = og * 4 + i;
      float acc = b64[o];
      const float* wp = w64 + o * 64;
#pragma unroll
      for (int cg = 0; cg < 16; ++cg) {
        float4 w4 = *(const float4*)(wp + 4 * cg);
        acc = fmaf(xv[4 * cg + 0], w4.x, acc);
        acc = fmaf(xv[4 * cg + 1], w4.y, acc);
        acc = fmaf(xv[4 * cg + 2], w4.z, acc);
        acc = fmaf(xv[4 * cg + 3], w4.w, acc);
      }
      t0[i] = acc;
    }
    *(float4*)(op + og * 4) = make_float4(t0[0], t0[1], t0[2], t0[3]);
  }
}

// ---------------------------------------------------------------------------
// Kernel 2: q/k/v projections, thread = one token (all 3 windows contiguous).
// q[c'] = sum_c ev[c] * w[c][c']  (uses transposed weights wT[p][c'][c])
// ---------------------------------------------------------------------------
__global__ __launch_bounds__(256) void k_qkv(const float* __restrict__ ex,
                                             const float* __restrict__ wT,
                                             float* __restrict__ q,
                                             float* __restrict__ k,
                                             float* __restrict__ v) {
  long t = (long)blockIdx.x * 256 + threadIdx.x;  // [0, 3*NPOS)
  float ev[64];
  const float* ep = ex + t * 64;
#pragma unroll
  for (int cg = 0; cg < 16; ++cg) {
    float4 e4 = *(const float4*)(ep + 4 * cg);
    ev[4 * cg + 0] = e4.x; ev[4 * cg + 1] = e4.y;
    ev[4 * cg + 2] = e4.z; ev[4 * cg + 3] = e4.w;
  }
#pragma unroll 1
  for (int pj = 0; pj < 3; ++pj) {
    const float* wp = wT + pj * 4096;
    float* op = (pj == 0 ? q : (pj == 1 ? k : v)) + t * 64;
#pragma unroll 1
    for (int og = 0; og < 16; ++og) {
      float t0[4];
#pragma unroll
      for (int i = 0; i < 4; ++i) {
        const float* wr_ = wp + (og * 4 + i) * 64;
        float acc = 0.f;
#pragma unroll
        for (int cg = 0; cg < 16; ++cg) {
          float4 w4 = *(const float4*)(wr_ + 4 * cg);
          acc = fmaf(ev[4 * cg + 0], w4.x, acc);
          acc = fmaf(ev[4 * cg + 1], w4.y, acc);
          acc = fmaf(ev[4 * cg + 2], w4.z, acc);
          acc = fmaf(ev[4 * cg + 3], w4.w, acc);
        }
        t0[i] = acc;
      }
      *(float4*)(op + og * 4) = make_float4(t0[0], t0[1], t0[2], t0[3]);
    }
  }
}

// ---------------------------------------------------------------------------
// Kernel 3: attention over one window. Block = 64-query tile of one group.
// 256 threads, each owns a 4x4 S/O register tile. Online softmax, fp32.
// ---------------------------------------------------------------------------
template <int L>
__global__ __launch_bounds__(256) void k_attn(const float* __restrict__ qg,
                                              const float* __restrict__ kg,
                                              const float* __restrict__ vg,
                                              float* __restrict__ og_,
                                              int nqt) {
  __shared__ float Qs[64][64];
  __shared__ float Ks[64][68];
  __shared__ float Vs[64][64];
  __shared__ float Ps[64][68];

  const int tid = threadIdx.x;
  const int g = blockIdx.x / nqt;
  const int qt = blockIdx.x % nqt;
  const long base = (long)g * L;
  const int ogr = tid >> 4;  // 0..15  (query group)
  const int kgr = tid & 15;  // 0..15  (key group)
  const int qi4 = ogr * 4, kj4 = kgr * 4;
  const int srow = tid >> 2;  // staging row 0..63
  const int sfq = tid & 3;

  // stage Q tile (zero-masked tail)
#pragma unroll
  for (int pass = 0; pass < 4; ++pass) {
    int c4 = (sfq + 4 * pass) * 4;
    int qi = qt * 64 + srow;
    float4 val = make_float4(0.f, 0.f, 0.f, 0.f);
    if (qi < L) val = *(const float4*)(qg + (base + qi) * 64 + c4);
    *(float4*)&Qs[srow][c4] = val;
  }

  float m[4], l[4], oa[4][4];
#pragma unroll
  for (int r = 0; r < 4; ++r) {
    m[r] = -1e30f; l[r] = 0.f;
#pragma unroll
    for (int u = 0; u < 4; ++u) oa[r][u] = 0.f;
  }

  constexpr int NCH = (L + 63) / 64;
  for (int ch = 0; ch < NCH; ++ch) {
    __syncthreads();  // previous PV done before overwriting K/V
#pragma unroll
    for (int pass = 0; pass < 4; ++pass) {
      int c4 = (sfq + 4 * pass) * 4;
      int tk = ch * 64 + srow;
      float4 kv = make_float4(0.f, 0.f, 0.f, 0.f);
      float4 vv = make_float4(0.f, 0.f, 0.f, 0.f);
      if (tk < L) {
        kv = *(const float4*)(kg + (base + tk) * 64 + c4);
        vv = *(const float4*)(vg + (base + tk) * 64 + c4);
      }
      *(float4*)&Ks[srow][c4] = kv;
      *(float4*)&Vs[srow][c4] = vv;
    }
    __syncthreads();

    // S = Q K^T
    float s[4][4];
#pragma unroll
    for (int r = 0; r < 4; ++r)
#pragma unroll
      for (int u = 0; u < 4; ++u) s[r][u] = 0.f;

#pragma unroll 4
    for (int cg = 0; cg < 16; ++cg) {
      float qv[4][4], kv[4][4];
#pragma unroll
      for (int r = 0; r < 4; ++r) {
        float4 q4 = *(const float4*)&Qs[qi4 + r][cg * 4];
        qv[r][0] = q4.x; qv[r][1] = q4.y; qv[r][2] = q4.z; qv[r][3] = q4.w;
      }
#pragma unroll
      for (int u = 0; u < 4; ++u) {
        float4 k4 = *(const float4*)&Ks[kj4 + u][cg * 4];
        kv[u][0] = k4.x; kv[u][1] = k4.y; kv[u][2] = k4.z; kv[u][3] = k4.w;
      }
#pragma unroll
      for (int r = 0; r < 4; ++r)
#pragma unroll
        for (int u = 0; u < 4; ++u) {
          float a = s[r][u];
          a = fmaf(qv[r][0], kv[u][0], a);
          a = fmaf(qv[r][1], kv[u][1], a);
          a = fmaf(qv[r][2], kv[u][2], a);
          a = fmaf(qv[r][3], kv[u][3], a);
          s[r][u] = a;
        }
    }
    // scale + key mask
#pragma unroll
    for (int u = 0; u < 4; ++u) {
      int kidx = ch * 64 + kj4 + u;
#pragma unroll
      for (int r = 0; r < 4; ++r)
        s[r][u] = (kidx < L) ? s[r][u] * 0.125f : -1e30f;
    }
    // online softmax (row = 16 consecutive lanes)
    float red[4];
#pragma unroll
    for (int r = 0; r < 4; ++r)
      red[r] = fmaxf(fmaxf(s[r][0], s[r][1]), fmaxf(s[r][2], s[r][3]));
#pragma unroll
    for (int d = 1; d < 16; d <<= 1)
#pragma unroll
      for (int r = 0; r < 4; ++r)
        red[r] = fmaxf(red[r], __shfl_xor(red[r], d));
    float fs[4];
#pragma unroll
    for (int r = 0; r < 4; ++r) {
      float mn = fmaxf(m[r], red[r]);
      fs[r] = __expf(m[r] - mn);
      m[r] = mn;
      float rs = 0.f;
#pragma unroll
      for (int u = 0; u < 4; ++u) {
        float p = __expf(s[r][u] - mn);
        s[r][u] = p;
        rs += p;
      }
      red[r] = rs;
#pragma unroll
      for (int u = 0; u < 4; ++u) oa[r][u] *= fs[r];
    }
#pragma unroll
    for (int d = 1; d < 16; d <<= 1)
#pragma unroll
      for (int r = 0; r < 4; ++r) red[r] += __shfl_xor(red[r], d);
#pragma unroll
    for (int r = 0; r < 4; ++r) l[r] = l[r] * fs[r] + red[r];

    // write P transposed: Ps[key][query]
#pragma unroll
    for (int u = 0; u < 4; ++u)
      *(float4*)&Ps[kj4 + u][qi4] =
          make_float4(s[0][u], s[1][u], s[2][u], s[3][u]);
    __syncthreads();

    // O += P V
#pragma unroll 4
    for (int j = 0; j < 64; ++j) {
      float4 p4 = *(const float4*)&Ps[j][qi4];
      float4 v4 = *(const float4*)&Vs[j][kj4];
      float pr[4] = {p4.x, p4.y, p4.z, p4.w};
      float vr[4] = {v4.x, v4.y, v4.z, v4.w};
#pragma unroll
      for (int r = 0; r < 4; ++r)
#pragma unroll
        for (int u = 0; u < 4; ++u)
          oa[r][u] = fmaf(pr[r], vr[u], oa[r][u]);
    }
  }

  // store O (token-major)
#pragma unroll
  for (int r = 0; r < 4; ++r) {
    int qi = qt * 64 + qi4 + r;
    if (qi < L) {
      float inv = 1.0f / l[r];
      *(float4*)(og_ + (base + qi) * 64 + kj4) =
          make_float4(oa[r][0] * inv, oa[r][1] * inv, oa[r][2] * inv,
                      oa[r][3] * inv);
    }
  }
}

// ---------------------------------------------------------------------------
// Kernel 4: mask_fusion1 -> res conv -> mask_fusion2 -> fus conv.
// Block handles 64 consecutive positions (same n since 5184 % 64 == 0).
// ---------------------------------------------------------------------------
__global__ __launch_bounds__(256) void k_fuse(
    const float* __restrict__ x, const float* __restrict__ ex,
    const float* __restrict__ att, const float* __restrict__ res_w,
    const float* __restrict__ res_b, const float* __restrict__ fus_w,
    const float* __restrict__ fus_b, const float* __restrict__ m1aw,
    const float* __restrict__ m1ab, const float* __restrict__ m1bw,
    const float* __restrict__ m1bb, const float* __restrict__ m2aw,
    const float* __restrict__ m2ab, const float* __restrict__ m2bw,
    const float* __restrict__ m2bb, float* __restrict__ out) {
  __shared__ float fT[192][68];  // [channel][pos] ; reused as out2T[64][68]
  const int tid = threadIdx.x;
  const int posb = blockIdx.x * 64;
  const int n = posb / HW;
  const int posn = posb % HW;

  // ---- phase A: mask fusion 1 per position; wave handles 16 positions ----
  {
    const int wv = tid >> 6, lane = tid & 63;
    float w1a0 = m1aw[0], w1a1 = m1aw[1], w1a2 = m1aw[2], w1a3 = m1aw[3];
    float b1a0 = m1ab[0], b1a1 = m1ab[1];
    float w1b0 = m1bw[0], w1b1 = m1bw[1], w1b2 = m1bw[2], w1b3 = m1bw[3];
    float b1b0 = m1bb[0], b1b1 = m1bb[1];
    for (int pp = 0; pp < 16; ++pp) {
      int pl = wv * 16 + pp;
      int pos = posn + pl;
      int h = pos / CW, wcol = pos % CW;
      auto tok = [&](int S, int W) -> int {
        int wr = h / S, kx = h % S, wcq = wcol / S, ky = wcol % S;
        return kx * (S * W * W) + ky * (W * W) + wr * W + wcq;
      };
      int j0 = tok(36, 2), j1 = tok(18, 4), j2 = tok(12, 6);
      long t0 = ((long)n * HW + j0) * 64 + lane;
      long t1 = ((long)NPOS + (long)n * HW + j1) * 64 + lane;
      long t2 = (2L * NPOS + (long)n * HW + j2) * 64 + lane;
      float av0 = att[t0], av1 = att[t1], av2 = att[t2];
      float ev0 = ex[t0], ev1 = ex[t1], ev2 = ex[t2];
      float mxa = fmaxf(fmaxf(av0, av1), av2), sma = av0 + av1 + av2;
      float mxe = fmaxf(fmaxf(ev0, ev1), ev2), sme = ev0 + ev1 + ev2;
#pragma unroll
      for (int d = 1; d < 64; d <<= 1) {
        mxa = fmaxf(mxa, __shfl_xor(mxa, d));
        sma += __shfl_xor(sma, d);
        mxe = fmaxf(mxe, __shfl_xor(mxe, d));
        sme += __shfl_xor(sme, d);
      }
      float mna = sma * (1.f / 192.f), mne = sme * (1.f / 192.f);
      float ca0 = fmaf(w1a0, mxa, fmaf(w1a1, mna, b1a0));
      float ca1 = fmaf(w1a2, mxa, fmaf(w1a3, mna, b1a1));
      float cb0 = fmaf(w1b0, mxe, fmaf(w1b1, mne, b1b0));
      float cb1 = fmaf(w1b2, mxe, fmaf(w1b3, mne, b1b1));
      bool mk = (ca0 * cb0 + ca1 * cb1) > 0.f;
      fT[lane][pl] = mk ? ev0 : av0;
      fT[64 + lane][pl] = mk ? ev1 : av1;
      fT[128 + lane][pl] = mk ? ev2 : av2;
    }
  }
  __syncthreads();

  // ---- phase B: res conv GEMM (192 -> 64), thread tile 4 outs x 4 pos ----
  const int ogi = tid & 15, pgi = tid >> 4;
  const int o4 = ogi * 4, p4 = pgi * 4;
  float acc[4][4];
#pragma unroll
  for (int i = 0; i < 4; ++i) {
    float b = res_b[o4 + i];
#pragma unroll
    for (int jj = 0; jj < 4; ++jj) acc[i][jj] = b;
  }
#pragma unroll 2
  for (int cg = 0; cg < 48; ++cg) {
    int cc = cg * 4;
    float wv4[4][4], fv4[4][4];
#pragma unroll
    for (int i = 0; i < 4; ++i) {
      float4 w4 = *(const float4*)(res_w + (o4 + i) * 192 + cc);
      wv4[i][0] = w4.x; wv4[i][1] = w4.y; wv4[i][2] = w4.z; wv4[i][3] = w4.w;
    }
#pragma unroll
    for (int u = 0; u < 4; ++u) {
      float4 f4 = *(const float4*)&fT[cc + u][p4];
      fv4[u][0] = f4.x; fv4[u][1] = f4.y; fv4[u][2] = f4.z; fv4[u][3] = f4.w;
    }
#pragma unroll
    for (int i = 0; i < 4; ++i)
#pragma unroll
      for (int jj = 0; jj < 4; ++jj) {
        float a = acc[i][jj];
        a = fmaf(wv4[i][0], fv4[0][jj], a);
        a = fmaf(wv4[i][1], fv4[1][jj], a);
        a = fmaf(wv4[i][2], fv4[2][jj], a);
        a = fmaf(wv4[i][3], fv4[3][jj], a);
        acc[i][jj] = a;
      }
  }

  // ---- phase C: mask fusion 2 (pool over 64 channels per position) ----
  float rmx[4], rsm[4];
#pragma unroll
  for (int jj = 0; jj < 4; ++jj) {
    rmx[jj] = fmaxf(fmaxf(acc[0][jj], acc[1][jj]), fmaxf(acc[2][jj], acc[3][jj]));
    rsm[jj] = acc[0][jj] + acc[1][jj] + acc[2][jj] + acc[3][jj];
  }
#pragma unroll
  for (int d = 1; d < 16; d <<= 1)
#pragma unroll
    for (int jj = 0; jj < 4; ++jj) {
      rmx[jj] = fmaxf(rmx[jj], __shfl_xor(rmx[jj], d));
      rsm[jj] += __shfl_xor(rsm[jj], d);
    }
  const float* xp = x + (long)n * CC * HW + posn;
  float xv[4][4];
#pragma unroll
  for (int i = 0; i < 4; ++i)
#pragma unroll
    for (int jj = 0; jj < 4; ++jj)
      xv[i][jj] = xp[(o4 + i) * HW + p4 + jj];
  float xmx[4], xsm[4];
#pragma unroll
  for (int jj = 0; jj < 4; ++jj) {
    xmx[jj] = fmaxf(fmaxf(xv[0][jj], xv[1][jj]), fmaxf(xv[2][jj], xv[3][jj]));
    xsm[jj] = xv[0][jj] + xv[1][jj] + xv[2][jj] + xv[3][jj];
  }
#pragma unroll
  for (int d = 1; d < 16; d <<= 1)
#pragma unroll
    for (int jj = 0; jj < 4; ++jj) {
      xmx[jj] = fmaxf(xmx[jj], __shfl_xor(xmx[jj], d));
      xsm[jj] += __shfl_xor(xsm[jj], d);
    }
  float w2a0 = m2aw[0], w2a1 = m2aw[1], w2a2 = m2aw[2], w2a3 = m2aw[3];
  float b2a0 = m2ab[0], b2a1 = m2ab[1];
  float w2b0 = m2bw[0], w2b1 = m2bw[1], w2b2 = m2bw[2], w2b3 = m2bw[3];
  float b2b0 = m2bb[0], b2b1 = m2bb[1];
  bool mk2[4];
#pragma unroll
  for (int jj = 0; jj < 4; ++jj) {
    float rmn = rsm[jj] * (1.f / 64.f), xmn = xsm[jj] * (1.f / 64.f);
    float ca0 = fmaf(w2a0, rmx[jj], fmaf(w2a1, rmn, b2a0));
    float ca1 = fmaf(w2a2, rmx[jj], fmaf(w2a3, rmn, b2a1));
    float cb0 = fmaf(w2b0, xmx[jj], fmaf(w2b1, xmn, b2b0));
    float cb1 = fmaf(w2b2, xmx[jj], fmaf(w2b3, xmn, b2b1));
    mk2[jj] = (ca0 * cb0 + ca1 * cb1) > 0.f;
  }
  __syncthreads();  // everyone done reading fT (phase B)
#pragma unroll
  for (int i = 0; i < 4; ++i)
#pragma unroll
    for (int jj = 0; jj < 4; ++jj)
      fT[o4 + i][p4 + jj] = mk2[jj] ? xv[i][jj] : acc[i][jj];
  __syncthreads();

  // ---- phase D: fus conv GEMM (64 -> 64) + store ----
  float a2[4][4];
#pragma unroll
  for (int i = 0; i < 4; ++i) {
    float b = fus_b[o4 + i];
#pragma unroll
    for (int jj = 0; jj < 4; ++jj) a2[i][jj] = b;
  }
#pragma unroll 2
  for (int cg = 0; cg < 16; ++cg) {
    int cc = cg * 4;
    float wv4[4][4], fv4[4][4];
#pragma unroll
    for (int i = 0; i < 4; ++i) {
      float4 w4 = *(const float4*)(fus_w + (o4 + i) * 64 + cc);
      wv4[i][0] = w4.x; wv4[i][1] = w4.y; wv4[i][2] = w4.z; wv4[i][3] = w4.w;
    }
#pragma unroll
    for (int u = 0; u < 4; ++u) {
      float4 f4 = *(const float4*)&fT[cc + u][p4];
      fv4[u][0] = f4.x; fv4[u][1] = f4.y; fv4[u][2] = f4.z; fv4[u][3] = f4.w;
    }
#pragma unroll
    for (int i = 0; i < 4; ++i)
#pragma unroll
      for (int jj = 0; jj < 4; ++jj) {
        float a = a2[i][jj];
        a = fmaf(wv4[i][0], fv4[0][jj], a);
        a = fmaf(wv4[i][1], fv4[1][jj], a);
        a = fmaf(wv4[i][2], fv4[2][jj], a);
        a = fmaf(wv4[i][3], fv4[3][jj], a);
        a2[i][jj] = a;
      }
  }
#pragma unroll
  for (int i = 0; i < 4; ++i)
    *(float4*)(out + ((long)n * CC + o4 + i) * HW + posn + p4) =
        make_float4(a2[i][0], a2[i][1], a2[i][2], a2[i][3]);
}

// ---------------------------------------------------------------------------
extern "C" void kernel_launch(void* const* d_in, const int* in_sizes, int n_in,
                              void* d_out, int out_size, void* d_ws,
                              size_t ws_size, hipStream_t stream) {
  (void)in_sizes; (void)n_in; (void)out_size;
  const float* x      = (const float*)d_in[0];
  const float* exp_w  = (const float*)d_in[1];
  const float* exp_b  = (const float*)d_in[2];
  const float* res_w  = (const float*)d_in[3];
  const float* res_b  = (const float*)d_in[4];
  const float* fus_w  = (const float*)d_in[5];
  const float* fus_b  = (const float*)d_in[6];
  const float* wq     = (const float*)d_in[7];
  const float* wk     = (const float*)d_in[8];
  const float* wv     = (const float*)d_in[9];
  const float* m1aw   = (const float*)d_in[10];
  const float* m1ab   = (const float*)d_in[11];
  const float* m1bw   = (const float*)d_in[12];
  const float* m1bb   = (const float*)d_in[13];
  const float* m2aw   = (const float*)d_in[14];
  const float* m2ab   = (const float*)d_in[15];
  const float* m2bw   = (const float*)d_in[16];
  const float* m2bb   = (const float*)d_in[17];

  const size_t needF = 5 * (size_t)TOKF + 3 * 4096;
  if (ws_size < needF * sizeof(float)) return;  // insufficient scratch
  float* ws = (float*)d_ws;
  float* ex = ws;
  float* qb = ex + TOKF;
  float* kb = qb + TOKF;
  float* vb = kb + TOKF;
  float* ob = vb + TOKF;
  float* wT = ob + TOKF;

  k_wT<<<48, 256, 0, stream>>>(wq, wk, wv, wT);

  k_expand<2, 36><<<81, 256, 0, stream>>>(x, exp_w, exp_b, ex);
  k_expand<4, 18><<<81, 256, 0, stream>>>(x, exp_w + 64 * 64, exp_b + 64,
                                          ex + (long)NPOS * 64);
  k_expand<6, 12><<<81, 256, 0, stream>>>(x, exp_w + 2 * 64 * 64, exp_b + 128,
                                          ex + 2L * NPOS * 64);

  k_qkv<<<243, 256, 0, stream>>>(ex, wT, qb, kb, vb);

  const long w1 = (long)NPOS * 64, w2 = 2L * NPOS * 64;
  k_attn<1296><<<16 * 21, 256, 0, stream>>>(qb, kb, vb, ob, 21);
  k_attn<324><<<64 * 6, 256, 0, stream>>>(qb + w1, kb + w1, vb + w1, ob + w1, 6);
  k_attn<144><<<144 * 3, 256, 0, stream>>>(qb + w2, kb + w2, vb + w2, ob + w2, 3);

  k_fuse<<<324, 256, 0, stream>>>(x, ex, ob, res_w, res_b, fus_w, fus_b, m1aw,
                                  m1ab, m1bw, m1bb, m2aw, m2ab, m2bw, m2bb,
                                  (float*)d_out);
}

// Round 2
// 392.568 us; speedup vs baseline: 1.6957x; 1.6957x over previous
//
#include <hip/hip_runtime.h>

constexpr int CN = 4;          // batch
constexpr int CC = 64;         // channels per window
constexpr int CH = 72, CW = 72;
constexpr int HW = CH * CW;    // 5184
constexpr int NPOS = CN * HW;  // 20736 tokens per window
constexpr long TOKF = 3L * NPOS * 64;  // floats in one [3][NPOS][64] array

// float4-slot XOR swizzle for [rows][64] fp32 LDS arrays (16 slots/row).
// dword offset of (row, slot): row*64 + ((slot ^ (row&15))*4)
#define SWZ(row, slot) (((row) << 6) + ((((slot) ^ ((row) & 15))) << 2))

// ---------------------------------------------------------------------------
// Kernel 1: expand conv (3 windows) + wq/wk/wv transpose, one launch.
// blocks [0,243): expand (81 per window). blocks [243,291): wT.
// ---------------------------------------------------------------------------
template <int WW, int SS>
__device__ __forceinline__ void expand_body(const float* __restrict__ x,
                                            const float* __restrict__ w64,
                                            const float* __restrict__ b64,
                                            float* __restrict__ out, int pg) {
  int n = pg / HW;
  int pos = pg - n * HW;
  int h = pos / CW, wcol = pos % CW;

  float xv[64];
  const float* xp = x + (long)n * CC * HW + pos;
#pragma unroll
  for (int c = 0; c < 64; ++c) xv[c] = xp[c * HW];

  int wr = h / SS, kx = h % SS, wcq = wcol / SS, ky = wcol % SS;
  int j = kx * (SS * WW * WW) + ky * (WW * WW) + wr * WW + wcq;
  float* op = out + ((long)n * HW + j) * 64;

#pragma unroll 1
  for (int og = 0; og < 16; ++og) {
    float t0[4];
#pragma unroll
    for (int i = 0; i < 4; ++i) {
      int o = og * 4 + i;
      float acc = b64[o];
      const float* wp = w64 + o * 64;
#pragma unroll
      for (int cg = 0; cg < 16; ++cg) {
        float4 w4 = *(const float4*)(wp + 4 * cg);
        acc = fmaf(xv[4 * cg + 0], w4.x, acc);
        acc = fmaf(xv[4 * cg + 1], w4.y, acc);
        acc = fmaf(xv[4 * cg + 2], w4.z, acc);
        acc = fmaf(xv[4 * cg + 3], w4.w, acc);
      }
      t0[i] = acc;
    }
    *(float4*)(op + og * 4) = make_float4(t0[0], t0[1], t0[2], t0[3]);
  }
}

__global__ __launch_bounds__(256) void k_prep(
    const float* __restrict__ x, const float* __restrict__ exp_w,
    const float* __restrict__ exp_b, const float* __restrict__ wq,
    const float* __restrict__ wk, const float* __restrict__ wv,
    float* __restrict__ ex, float* __restrict__ wT) {
  int b = blockIdx.x;
  if (b >= 243) {  // transpose part
    int i = (b - 243) * 256 + threadIdx.x;  // [0, 12288)
    int m = i >> 12;
    int r = i & 4095;
    int cp = r >> 6, c = r & 63;
    const float* src = (m == 0) ? wq : ((m == 1) ? wk : wv);
    wT[i] = src[c * 64 + cp];
    return;
  }
  int wi = b / 81;
  int pg = (b - wi * 81) * 256 + threadIdx.x;  // [0, NPOS)
  if (wi == 0)
    expand_body<2, 36>(x, exp_w, exp_b, ex, pg);
  else if (wi == 1)
    expand_body<4, 18>(x, exp_w + 4096, exp_b + 64, ex + (long)NPOS * 64, pg);
  else
    expand_body<6, 12>(x, exp_w + 8192, exp_b + 128, ex + 2L * NPOS * 64, pg);
}

// ---------------------------------------------------------------------------
// Kernel 2: q/k/v projections as LDS-tiled GEMM.
// Block = 64 tokens x 192 outs (3 projections). Thread tile 4 out x 4 tok.
// ---------------------------------------------------------------------------
__global__ __launch_bounds__(256) void k_qkv(const float* __restrict__ ex,
                                             const float* __restrict__ wT,
                                             float* __restrict__ q,
                                             float* __restrict__ k,
                                             float* __restrict__ v) {
  __shared__ float Es[4096];    // 64 tokens x 64 ch, swizzled
  __shared__ float wls[12288];  // 192 rows x 64 ch, swizzled

  const int tid = threadIdx.x;
  const long tok0 = (long)blockIdx.x * 64;
  const int srow = tid >> 2, sfq = tid & 3;

  // stage token tile
#pragma unroll
  for (int p = 0; p < 4; ++p) {
    int slot = 4 * p + sfq;
    float4 val = *(const float4*)(ex + (tok0 + srow) * 64 + slot * 4);
    *(float4*)&Es[SWZ(srow, slot)] = val;
  }
  // stage all 3 transposed weight matrices
#pragma unroll
  for (int it = 0; it < 12; ++it) {
    int i = it * 256 + tid;  // [0, 3072) float4 index
    int row = i >> 4, slot = i & 15;
    *(float4*)&wls[SWZ(row, slot)] = ((const float4*)wT)[i];
  }
  __syncthreads();

  const int og = tid & 15, tg = tid >> 4;
  const int o4 = og * 4, t4 = tg * 4;

#pragma unroll 1
  for (int pj = 0; pj < 3; ++pj) {
    float acc[4][4];
#pragma unroll
    for (int i = 0; i < 4; ++i)
#pragma unroll
      for (int jj = 0; jj < 4; ++jj) acc[i][jj] = 0.f;

#pragma unroll 4
    for (int cg = 0; cg < 16; ++cg) {
      float wv4[4][4], ev4[4][4];
#pragma unroll
      for (int i = 0; i < 4; ++i) {
        float4 w4 = *(const float4*)&wls[SWZ(pj * 64 + o4 + i, cg)];
        wv4[i][0] = w4.x; wv4[i][1] = w4.y; wv4[i][2] = w4.z; wv4[i][3] = w4.w;
      }
#pragma unroll
      for (int jj = 0; jj < 4; ++jj) {
        float4 e4 = *(const float4*)&Es[SWZ(t4 + jj, cg)];
        ev4[jj][0] = e4.x; ev4[jj][1] = e4.y; ev4[jj][2] = e4.z; ev4[jj][3] = e4.w;
      }
#pragma unroll
      for (int i = 0; i < 4; ++i)
#pragma unroll
        for (int jj = 0; jj < 4; ++jj) {
          float a = acc[i][jj];
          a = fmaf(wv4[i][0], ev4[jj][0], a);
          a = fmaf(wv4[i][1], ev4[jj][1], a);
          a = fmaf(wv4[i][2], ev4[jj][2], a);
          a = fmaf(wv4[i][3], ev4[jj][3], a);
          acc[i][jj] = a;
        }
    }
    float* op = (pj == 0 ? q : (pj == 1 ? k : v));
#pragma unroll
    for (int jj = 0; jj < 4; ++jj)
      *(float4*)(op + (tok0 + t4 + jj) * 64 + o4) =
          make_float4(acc[0][jj], acc[1][jj], acc[2][jj], acc[3][jj]);
  }
}

// ---------------------------------------------------------------------------
// Kernel 3: merged attention, all 3 windows in one launch (1152 blocks).
// Block = 64-query tile; 256 threads, 4x4 per-thread S/O tiles; fp32;
// XOR-swizzled LDS; register double-buffered K/V global staging.
// ---------------------------------------------------------------------------
__global__ __launch_bounds__(256) void k_attn(const float* __restrict__ qg,
                                              const float* __restrict__ kg,
                                              const float* __restrict__ vg,
                                              float* __restrict__ og_) {
  __shared__ float Qs[4096];
  __shared__ float Ks[4096];
  __shared__ float Vs[4096];
  __shared__ float Ps[4096];

  const int tid = threadIdx.x;
  int b = blockIdx.x;
  int L, g, qt, NCH;
  long tokbase;
  if (b < 336) {
    L = 1296; NCH = 21; g = b / 21; qt = b - g * 21;
    tokbase = (long)g * 1296;
  } else if (b < 720) {
    int t = b - 336;
    L = 324; NCH = 6; g = t / 6; qt = t - g * 6;
    tokbase = (long)NPOS + (long)g * 324;
  } else {
    int t = b - 720;
    L = 144; NCH = 3; g = t / 3; qt = t - g * 3;
    tokbase = 2L * NPOS + (long)g * 144;
  }

  const int ogr = tid >> 4;   // query group 0..15
  const int kgr = tid & 15;   // key group 0..15
  const int qi4 = ogr * 4, kj4 = kgr * 4;
  const int srow = tid >> 2;  // staging row 0..63
  const int sfq = tid & 3;

  // stage Q tile (zero-masked tail), swizzled
  {
    int qi = qt * 64 + srow;
#pragma unroll
    for (int p = 0; p < 4; ++p) {
      int slot = 4 * p + sfq;
      float4 val = make_float4(0.f, 0.f, 0.f, 0.f);
      if (qi < L) val = *(const float4*)(qg + (tokbase + qi) * 64 + slot * 4);
      *(float4*)&Qs[SWZ(srow, slot)] = val;
    }
  }

  float m[4], l[4], oa[4][4];
#pragma unroll
  for (int r = 0; r < 4; ++r) {
    m[r] = -1e30f; l[r] = 0.f;
#pragma unroll
    for (int u = 0; u < 4; ++u) oa[r][u] = 0.f;
  }

  float4 pk[4], pv[4];
  auto loadKV = [&](int ch) {
    int tk = ch * 64 + srow;
#pragma unroll
    for (int p = 0; p < 4; ++p) {
      if (tk < L) {
        long a = (tokbase + tk) * 64 + (4 * p + sfq) * 4;
        pk[p] = *(const float4*)(kg + a);
        pv[p] = *(const float4*)(vg + a);
      } else {
        pk[p] = make_float4(0.f, 0.f, 0.f, 0.f);
        pv[p] = make_float4(0.f, 0.f, 0.f, 0.f);
      }
    }
  };
  loadKV(0);

  for (int ch = 0; ch < NCH; ++ch) {
    __syncthreads();  // previous chunk's readers done
#pragma unroll
    for (int p = 0; p < 4; ++p) {
      int slot = 4 * p + sfq;
      *(float4*)&Ks[SWZ(srow, slot)] = pk[p];
      *(float4*)&Vs[SWZ(srow, slot)] = pv[p];
    }
    __syncthreads();
    if (ch + 1 < NCH) loadKV(ch + 1);  // prefetch next chunk into regs

    // S = Q K^T
    float s[4][4];
#pragma unroll
    for (int r = 0; r < 4; ++r)
#pragma unroll
      for (int u = 0; u < 4; ++u) s[r][u] = 0.f;

#pragma unroll 4
    for (int cg = 0; cg < 16; ++cg) {
      float qv[4][4], kv[4][4];
#pragma unroll
      for (int r = 0; r < 4; ++r) {
        float4 q4 = *(const float4*)&Qs[SWZ(qi4 + r, cg)];
        qv[r][0] = q4.x; qv[r][1] = q4.y; qv[r][2] = q4.z; qv[r][3] = q4.w;
      }
#pragma unroll
      for (int u = 0; u < 4; ++u) {
        float4 k4 = *(const float4*)&Ks[SWZ(kj4 + u, cg)];
        kv[u][0] = k4.x; kv[u][1] = k4.y; kv[u][2] = k4.z; kv[u][3] = k4.w;
      }
#pragma unroll
      for (int r = 0; r < 4; ++r)
#pragma unroll
        for (int u = 0; u < 4; ++u) {
          float a = s[r][u];
          a = fmaf(qv[r][0], kv[u][0], a);
          a = fmaf(qv[r][1], kv[u][1], a);
          a = fmaf(qv[r][2], kv[u][2], a);
          a = fmaf(qv[r][3], kv[u][3], a);
          s[r][u] = a;
        }
    }
    // scale + key mask
#pragma unroll
    for (int u = 0; u < 4; ++u) {
      int kidx = ch * 64 + kj4 + u;
#pragma unroll
      for (int r = 0; r < 4; ++r)
        s[r][u] = (kidx < L) ? s[r][u] * 0.125f : -1e30f;
    }
    // online softmax (row = 16 consecutive lanes)
    float red[4];
#pragma unroll
    for (int r = 0; r < 4; ++r)
      red[r] = fmaxf(fmaxf(s[r][0], s[r][1]), fmaxf(s[r][2], s[r][3]));
#pragma unroll
    for (int d = 1; d < 16; d <<= 1)
#pragma unroll
      for (int r = 0; r < 4; ++r)
        red[r] = fmaxf(red[r], __shfl_xor(red[r], d));
    float fs[4];
#pragma unroll
    for (int r = 0; r < 4; ++r) {
      float mn = fmaxf(m[r], red[r]);
      fs[r] = __expf(m[r] - mn);
      m[r] = mn;
      float rs = 0.f;
#pragma unroll
      for (int u = 0; u < 4; ++u) {
        float p = __expf(s[r][u] - mn);
        s[r][u] = p;
        rs += p;
      }
      red[r] = rs;
#pragma unroll
      for (int u = 0; u < 4; ++u) oa[r][u] *= fs[r];
    }
#pragma unroll
    for (int d = 1; d < 16; d <<= 1)
#pragma unroll
      for (int r = 0; r < 4; ++r) red[r] += __shfl_xor(red[r], d);
#pragma unroll
    for (int r = 0; r < 4; ++r) l[r] = l[r] * fs[r] + red[r];

    // write P transposed: Ps[key][query], swizzled (slot index = ogr)
#pragma unroll
    for (int u = 0; u < 4; ++u)
      *(float4*)&Ps[SWZ(kj4 + u, ogr)] =
          make_float4(s[0][u], s[1][u], s[2][u], s[3][u]);
    __syncthreads();

    // O += P V
#pragma unroll 4
    for (int j = 0; j < 64; ++j) {
      float4 p4 = *(const float4*)&Ps[SWZ(j, ogr)];
      float4 v4 = *(const float4*)&Vs[SWZ(j, kgr)];
      float pr[4] = {p4.x, p4.y, p4.z, p4.w};
      float vr[4] = {v4.x, v4.y, v4.z, v4.w};
#pragma unroll
      for (int r = 0; r < 4; ++r)
#pragma unroll
        for (int u = 0; u < 4; ++u)
          oa[r][u] = fmaf(pr[r], vr[u], oa[r][u]);
    }
  }

  // store O (token-major)
#pragma unroll
  for (int r = 0; r < 4; ++r) {
    int qi = qt * 64 + qi4 + r;
    if (qi < L) {
      float inv = 1.0f / l[r];
      *(float4*)(og_ + (tokbase + qi) * 64 + kj4) =
          make_float4(oa[r][0] * inv, oa[r][1] * inv, oa[r][2] * inv,
                      oa[r][3] * inv);
    }
  }
}

// ---------------------------------------------------------------------------
// Kernel 4: mask_fusion1 -> res conv -> mask_fusion2 -> fus conv.
// ---------------------------------------------------------------------------
__global__ __launch_bounds__(256) void k_fuse(
    const float* __restrict__ x, const float* __restrict__ ex,
    const float* __restrict__ att, const float* __restrict__ res_w,
    const float* __restrict__ res_b, const float* __restrict__ fus_w,
    const float* __restrict__ fus_b, const float* __restrict__ m1aw,
    const float* __restrict__ m1ab, const float* __restrict__ m1bw,
    const float* __restrict__ m1bb, const float* __restrict__ m2aw,
    const float* __restrict__ m2ab, const float* __restrict__ m2bw,
    const float* __restrict__ m2bb, float* __restrict__ out) {
  __shared__ float fT[192][68];
  const int tid = threadIdx.x;
  const int posb = blockIdx.x * 64;
  const int n = posb / HW;
  const int posn = posb % HW;

  // ---- phase A: mask fusion 1 per position; wave handles 16 positions ----
  {
    const int wv = tid >> 6, lane = tid & 63;
    float w1a0 = m1aw[0], w1a1 = m1aw[1], w1a2 = m1aw[2], w1a3 = m1aw[3];
    float b1a0 = m1ab[0], b1a1 = m1ab[1];
    float w1b0 = m1bw[0], w1b1 = m1bw[1], w1b2 = m1bw[2], w1b3 = m1bw[3];
    float b1b0 = m1bb[0], b1b1 = m1bb[1];
    for (int pp = 0; pp < 16; ++pp) {
      int pl = wv * 16 + pp;
      int pos = posn + pl;
      int h = pos / CW, wcol = pos % CW;
      auto tok = [&](int S, int W) -> int {
        int wr = h / S, kx = h % S, wcq = wcol / S, ky = wcol % S;
        return kx * (S * W * W) + ky * (W * W) + wr * W + wcq;
      };
      int j0 = tok(36, 2), j1 = tok(18, 4), j2 = tok(12, 6);
      long t0 = ((long)n * HW + j0) * 64 + lane;
      long t1 = ((long)NPOS + (long)n * HW + j1) * 64 + lane;
      long t2 = (2L * NPOS + (long)n * HW + j2) * 64 + lane;
      float av0 = att[t0], av1 = att[t1], av2 = att[t2];
      float ev0 = ex[t0], ev1 = ex[t1], ev2 = ex[t2];
      float mxa = fmaxf(fmaxf(av0, av1), av2), sma = av0 + av1 + av2;
      float mxe = fmaxf(fmaxf(ev0, ev1), ev2), sme = ev0 + ev1 + ev2;
#pragma unroll
      for (int d = 1; d < 64; d <<= 1) {
        mxa = fmaxf(mxa, __shfl_xor(mxa, d));
        sma += __shfl_xor(sma, d);
        mxe = fmaxf(mxe, __shfl_xor(mxe, d));
        sme += __shfl_xor(sme, d);
      }
      float mna = sma * (1.f / 192.f), mne = sme * (1.f / 192.f);
      float ca0 = fmaf(w1a0, mxa, fmaf(w1a1, mna, b1a0));
      float ca1 = fmaf(w1a2, mxa, fmaf(w1a3, mna, b1a1));
      float cb0 = fmaf(w1b0, mxe, fmaf(w1b1, mne, b1b0));
      float cb1 = fmaf(w1b2, mxe, fmaf(w1b3, mne, b1b1));
      bool mk = (ca0 * cb0 + ca1 * cb1) > 0.f;
      fT[lane][pl] = mk ? ev0 : av0;
      fT[64 + lane][pl] = mk ? ev1 : av1;
      fT[128 + lane][pl] = mk ? ev2 : av2;
    }
  }
  __syncthreads();

  // ---- phase B: res conv GEMM (192 -> 64), thread tile 4 outs x 4 pos ----
  const int ogi = tid & 15, pgi = tid >> 4;
  const int o4 = ogi * 4, p4 = pgi * 4;
  float acc[4][4];
#pragma unroll
  for (int i = 0; i < 4; ++i) {
    float b = res_b[o4 + i];
#pragma unroll
    for (int jj = 0; jj < 4; ++jj) acc[i][jj] = b;
  }
#pragma unroll 2
  for (int cg = 0; cg < 48; ++cg) {
    int cc = cg * 4;
    float wv4[4][4], fv4[4][4];
#pragma unroll
    for (int i = 0; i < 4; ++i) {
      float4 w4 = *(const float4*)(res_w + (o4 + i) * 192 + cc);
      wv4[i][0] = w4.x; wv4[i][1] = w4.y; wv4[i][2] = w4.z; wv4[i][3] = w4.w;
    }
#pragma unroll
    for (int u = 0; u < 4; ++u) {
      float4 f4 = *(const float4*)&fT[cc + u][p4];
      fv4[u][0] = f4.x; fv4[u][1] = f4.y; fv4[u][2] = f4.z; fv4[u][3] = f4.w;
    }
#pragma unroll
    for (int i = 0; i < 4; ++i)
#pragma unroll
      for (int jj = 0; jj < 4; ++jj) {
        float a = acc[i][jj];
        a = fmaf(wv4[i][0], fv4[0][jj], a);
        a = fmaf(wv4[i][1], fv4[1][jj], a);
        a = fmaf(wv4[i][2], fv4[2][jj], a);
        a = fmaf(wv4[i][3], fv4[3][jj], a);
        acc[i][jj] = a;
      }
  }

  // ---- phase C: mask fusion 2 ----
  float rmx[4], rsm[4];
#pragma unroll
  for (int jj = 0; jj < 4; ++jj) {
    rmx[jj] = fmaxf(fmaxf(acc[0][jj], acc[1][jj]), fmaxf(acc[2][jj], acc[3][jj]));
    rsm[jj] = acc[0][jj] + acc[1][jj] + acc[2][jj] + acc[3][jj];
  }
#pragma unroll
  for (int d = 1; d < 16; d <<= 1)
#pragma unroll
    for (int jj = 0; jj < 4; ++jj) {
      rmx[jj] = fmaxf(rmx[jj], __shfl_xor(rmx[jj], d));
      rsm[jj] += __shfl_xor(rsm[jj], d);
    }
  const float* xp = x + (long)n * CC * HW + posn;
  float xv[4][4];
#pragma unroll
  for (int i = 0; i < 4; ++i)
#pragma unroll
    for (int jj = 0; jj < 4; ++jj)
      xv[i][jj] = xp[(o4 + i) * HW + p4 + jj];
  float xmx[4], xsm[4];
#pragma unroll
  for (int jj = 0; jj < 4; ++jj) {
    xmx[jj] = fmaxf(fmaxf(xv[0][jj], xv[1][jj]), fmaxf(xv[2][jj], xv[3][jj]));
    xsm[jj] = xv[0][jj] + xv[1][jj] + xv[2][jj] + xv[3][jj];
  }
#pragma unroll
  for (int d = 1; d < 16; d <<= 1)
#pragma unroll
    for (int jj = 0; jj < 4; ++jj) {
      xmx[jj] = fmaxf(xmx[jj], __shfl_xor(xmx[jj], d));
      xsm[jj] += __shfl_xor(xsm[jj], d);
    }
  float w2a0 = m2aw[0], w2a1 = m2aw[1], w2a2 = m2aw[2], w2a3 = m2aw[3];
  float b2a0 = m2ab[0], b2a1 = m2ab[1];
  float w2b0 = m2bw[0], w2b1 = m2bw[1], w2b2 = m2bw[2], w2b3 = m2bw[3];
  float b2b0 = m2bb[0], b2b1 = m2bb[1];
  bool mk2[4];
#pragma unroll
  for (int jj = 0; jj < 4; ++jj) {
    float rmn = rsm[jj] * (1.f / 64.f), xmn = xsm[jj] * (1.f / 64.f);
    float ca0 = fmaf(w2a0, rmx[jj], fmaf(w2a1, rmn, b2a0));
    float ca1 = fmaf(w2a2, rmx[jj], fmaf(w2a3, rmn, b2a1));
    float cb0 = fmaf(w2b0, xmx[jj], fmaf(w2b1, xmn, b2b0));
    float cb1 = fmaf(w2b2, xmx[jj], fmaf(w2b3, xmn, b2b1));
    mk2[jj] = (ca0 * cb0 + ca1 * cb1) > 0.f;
  }
  __syncthreads();
#pragma unroll
  for (int i = 0; i < 4; ++i)
#pragma unroll
    for (int jj = 0; jj < 4; ++jj)
      fT[o4 + i][p4 + jj] = mk2[jj] ? xv[i][jj] : acc[i][jj];
  __syncthreads();

  // ---- phase D: fus conv GEMM (64 -> 64) + store ----
  float a2[4][4];
#pragma unroll
  for (int i = 0; i < 4; ++i) {
    float b = fus_b[o4 + i];
#pragma unroll
    for (int jj = 0; jj < 4; ++jj) a2[i][jj] = b;
  }
#pragma unroll 2
  for (int cg = 0; cg < 16; ++cg) {
    int cc = cg * 4;
    float wv4[4][4], fv4[4][4];
#pragma unroll
    for (int i = 0; i < 4; ++i) {
      float4 w4 = *(const float4*)(fus_w + (o4 + i) * 64 + cc);
      wv4[i][0] = w4.x; wv4[i][1] = w4.y; wv4[i][2] = w4.z; wv4[i][3] = w4.w;
    }
#pragma unroll
    for (int u = 0; u < 4; ++u) {
      float4 f4 = *(const float4*)&fT[cc + u][p4];
      fv4[u][0] = f4.x; fv4[u][1] = f4.y; fv4[u][2] = f4.z; fv4[u][3] = f4.w;
    }
#pragma unroll
    for (int i = 0; i < 4; ++i)
#pragma unroll
      for (int jj = 0; jj < 4; ++jj) {
        float a = a2[i][jj];
        a = fmaf(wv4[i][0], fv4[0][jj], a);
        a = fmaf(wv4[i][1], fv4[1][jj], a);
        a = fmaf(wv4[i][2], fv4[2][jj], a);
        a = fmaf(wv4[i][3], fv4[3][jj], a);
        a2[i][jj] = a;
      }
  }
#pragma unroll
  for (int i = 0; i < 4; ++i)
    *(float4*)(out + ((long)n * CC + o4 + i) * HW + posn + p4) =
        make_float4(a2[i][0], a2[i][1], a2[i][2], a2[i][3]);
}

// ---------------------------------------------------------------------------
extern "C" void kernel_launch(void* const* d_in, const int* in_sizes, int n_in,
                              void* d_out, int out_size, void* d_ws,
                              size_t ws_size, hipStream_t stream) {
  (void)in_sizes; (void)n_in; (void)out_size;
  const float* x      = (const float*)d_in[0];
  const float* exp_w  = (const float*)d_in[1];
  const float* exp_b  = (const float*)d_in[2];
  const float* res_w  = (const float*)d_in[3];
  const float* res_b  = (const float*)d_in[4];
  const float* fus_w  = (const float*)d_in[5];
  const float* fus_b  = (const float*)d_in[6];
  const float* wq     = (const float*)d_in[7];
  const float* wk     = (const float*)d_in[8];
  const float* wv     = (const float*)d_in[9];
  const float* m1aw   = (const float*)d_in[10];
  const float* m1ab   = (const float*)d_in[11];
  const float* m1bw   = (const float*)d_in[12];
  const float* m1bb   = (const float*)d_in[13];
  const float* m2aw   = (const float*)d_in[14];
  const float* m2ab   = (const float*)d_in[15];
  const float* m2bw   = (const float*)d_in[16];
  const float* m2bb   = (const float*)d_in[17];

  const size_t needF = 5 * (size_t)TOKF + 3 * 4096;
  if (ws_size < needF * sizeof(float)) return;
  float* ws = (float*)d_ws;
  float* ex = ws;
  float* qb = ex + TOKF;
  float* kb = qb + TOKF;
  float* vb = kb + TOKF;
  float* ob = vb + TOKF;
  float* wT = ob + TOKF;

  k_prep<<<291, 256, 0, stream>>>(x, exp_w, exp_b, wq, wk, wv, ex, wT);
  k_qkv<<<972, 256, 0, stream>>>(ex, wT, qb, kb, vb);
  k_attn<<<1152, 256, 0, stream>>>(qb, kb, vb, ob);
  k_fuse<<<324, 256, 0, stream>>>(x, ex, ob, res_w, res_b, fus_w, fus_b, m1aw,
                                  m1ab, m1bw, m1bb, m2aw, m2ab, m2bw, m2bb,
                                  (float*)d_out);
}

// Round 3
// 372.757 us; speedup vs baseline: 1.7858x; 1.0531x over previous
//
#include <hip/hip_runtime.h>

constexpr int CN = 4;          // batch
constexpr int CC = 64;         // channels per window
constexpr int CH = 72, CW = 72;
constexpr int HW = CH * CW;    // 5184
constexpr int NPOS = CN * HW;  // 20736 tokens per window
constexpr long TOKF = 3L * NPOS * 64;  // floats in one [3][NPOS][64] array

// float4-slot XOR swizzle for [rows][64] fp32 LDS arrays (16 slots/row).
// bank-quad = (slot ^ (row&15)) & 7 -> spread requires accessed rows to
// differ in their low bits (consecutive rows). Key mapping below ensures it.
#define SWZ(row, slot) (((row) << 6) + ((((slot) ^ ((row) & 15))) << 2))

// ---------------------------------------------------------------------------
// Kernel 1: expand conv (3 windows) + wq/wk/wv transpose, one launch.
// ---------------------------------------------------------------------------
template <int WW, int SS>
__device__ __forceinline__ void expand_body(const float* __restrict__ x,
                                            const float* __restrict__ w64,
                                            const float* __restrict__ b64,
                                            float* __restrict__ out, int pg) {
  int n = pg / HW;
  int pos = pg - n * HW;
  int h = pos / CW, wcol = pos % CW;

  float xv[64];
  const float* xp = x + (long)n * CC * HW + pos;
#pragma unroll
  for (int c = 0; c < 64; ++c) xv[c] = xp[c * HW];

  int wr = h / SS, kx = h % SS, wcq = wcol / SS, ky = wcol % SS;
  int j = kx * (SS * WW * WW) + ky * (WW * WW) + wr * WW + wcq;
  float* op = out + ((long)n * HW + j) * 64;

#pragma unroll 1
  for (int og = 0; og < 16; ++og) {
    float t0[4];
#pragma unroll
    for (int i = 0; i < 4; ++i) {
      int o = og * 4 + i;
      float acc = b64[o];
      const float* wp = w64 + o * 64;
#pragma unroll
      for (int cg = 0; cg < 16; ++cg) {
        float4 w4 = *(const float4*)(wp + 4 * cg);
        acc = fmaf(xv[4 * cg + 0], w4.x, acc);
        acc = fmaf(xv[4 * cg + 1], w4.y, acc);
        acc = fmaf(xv[4 * cg + 2], w4.z, acc);
        acc = fmaf(xv[4 * cg + 3], w4.w, acc);
      }
      t0[i] = acc;
    }
    *(float4*)(op + og * 4) = make_float4(t0[0], t0[1], t0[2], t0[3]);
  }
}

__global__ __launch_bounds__(256) void k_prep(
    const float* __restrict__ x, const float* __restrict__ exp_w,
    const float* __restrict__ exp_b, const float* __restrict__ wq,
    const float* __restrict__ wk, const float* __restrict__ wv,
    float* __restrict__ ex, float* __restrict__ wT) {
  int b = blockIdx.x;
  if (b >= 243) {  // transpose part
    int i = (b - 243) * 256 + threadIdx.x;  // [0, 12288)
    int m = i >> 12;
    int r = i & 4095;
    int cp = r >> 6, c = r & 63;
    const float* src = (m == 0) ? wq : ((m == 1) ? wk : wv);
    wT[i] = src[c * 64 + cp];
    return;
  }
  int wi = b / 81;
  int pg = (b - wi * 81) * 256 + threadIdx.x;  // [0, NPOS)
  if (wi == 0)
    expand_body<2, 36>(x, exp_w, exp_b, ex, pg);
  else if (wi == 1)
    expand_body<4, 18>(x, exp_w + 4096, exp_b + 64, ex + (long)NPOS * 64, pg);
  else
    expand_body<6, 12>(x, exp_w + 8192, exp_b + 128, ex + 2L * NPOS * 64, pg);
}

// ---------------------------------------------------------------------------
// Kernel 2: q/k/v projections as LDS-tiled GEMM.
// ---------------------------------------------------------------------------
__global__ __launch_bounds__(256) void k_qkv(const float* __restrict__ ex,
                                             const float* __restrict__ wT,
                                             float* __restrict__ q,
                                             float* __restrict__ k,
                                             float* __restrict__ v) {
  __shared__ float Es[4096];    // 64 tokens x 64 ch, swizzled
  __shared__ float wls[12288];  // 192 rows x 64 ch, swizzled

  const int tid = threadIdx.x;
  const long tok0 = (long)blockIdx.x * 64;
  const int srow = tid >> 2, sfq = tid & 3;

#pragma unroll
  for (int p = 0; p < 4; ++p) {
    int slot = 4 * p + sfq;
    float4 val = *(const float4*)(ex + (tok0 + srow) * 64 + slot * 4);
    *(float4*)&Es[SWZ(srow, slot)] = val;
  }
#pragma unroll
  for (int it = 0; it < 12; ++it) {
    int i = it * 256 + tid;  // [0, 3072) float4 index
    int row = i >> 4, slot = i & 15;
    *(float4*)&wls[SWZ(row, slot)] = ((const float4*)wT)[i];
  }
  __syncthreads();

  const int og = tid & 15, tg = tid >> 4;
  const int o4 = og * 4, t4 = tg * 4;

#pragma unroll 1
  for (int pj = 0; pj < 3; ++pj) {
    float acc[4][4];
#pragma unroll
    for (int i = 0; i < 4; ++i)
#pragma unroll
      for (int jj = 0; jj < 4; ++jj) acc[i][jj] = 0.f;

#pragma unroll 4
    for (int cg = 0; cg < 16; ++cg) {
      float wv4[4][4], ev4[4][4];
#pragma unroll
      for (int i = 0; i < 4; ++i) {
        float4 w4 = *(const float4*)&wls[SWZ(pj * 64 + o4 + i, cg)];
        wv4[i][0] = w4.x; wv4[i][1] = w4.y; wv4[i][2] = w4.z; wv4[i][3] = w4.w;
      }
#pragma unroll
      for (int jj = 0; jj < 4; ++jj) {
        float4 e4 = *(const float4*)&Es[SWZ(t4 + jj, cg)];
        ev4[jj][0] = e4.x; ev4[jj][1] = e4.y; ev4[jj][2] = e4.z; ev4[jj][3] = e4.w;
      }
#pragma unroll
      for (int i = 0; i < 4; ++i)
#pragma unroll
        for (int jj = 0; jj < 4; ++jj) {
          float a = acc[i][jj];
          a = fmaf(wv4[i][0], ev4[jj][0], a);
          a = fmaf(wv4[i][1], ev4[jj][1], a);
          a = fmaf(wv4[i][2], ev4[jj][2], a);
          a = fmaf(wv4[i][3], ev4[jj][3], a);
          acc[i][jj] = a;
        }
    }
    float* op = (pj == 0 ? q : (pj == 1 ? k : v));
#pragma unroll
    for (int jj = 0; jj < 4; ++jj)
      *(float4*)(op + (tok0 + t4 + jj) * 64 + o4) =
          make_float4(acc[0][jj], acc[1][jj], acc[2][jj], acc[3][jj]);
  }
}

// ---------------------------------------------------------------------------
// Kernel 3: merged attention. Key->thread mapping: thread (ogr,kgr) owns
// keys {kgr + 16u}, so each K-row ds_read touches 16 CONSECUTIVE rows ->
// all 8 bank-quads hit (was 2 with keys 4*kgr+u -> 8-way conflict).
// ---------------------------------------------------------------------------
__global__ __launch_bounds__(256) void k_attn(const float* __restrict__ qg,
                                              const float* __restrict__ kg,
                                              const float* __restrict__ vg,
                                              float* __restrict__ og_) {
  __shared__ float Qs[4096];
  __shared__ float Ks[4096];
  __shared__ float Vs[4096];
  __shared__ float Ps[4096];

  const int tid = threadIdx.x;
  int b = blockIdx.x;
  int L, g, qt, NCH;
  long tokbase;
  if (b < 336) {
    L = 1296; NCH = 21; g = b / 21; qt = b - g * 21;
    tokbase = (long)g * 1296;
  } else if (b < 720) {
    int t = b - 336;
    L = 324; NCH = 6; g = t / 6; qt = t - g * 6;
    tokbase = (long)NPOS + (long)g * 324;
  } else {
    int t = b - 720;
    L = 144; NCH = 3; g = t / 3; qt = t - g * 3;
    tokbase = 2L * NPOS + (long)g * 144;
  }

  const int ogr = tid >> 4;   // query group 0..15 (queries 4*ogr..4*ogr+3)
  const int kgr = tid & 15;   // key lane 0..15 (keys kgr+16u) / channel group
  const int qi4 = ogr * 4, kj4 = kgr * 4;
  const int srow = tid >> 2;  // staging row 0..63
  const int sfq = tid & 3;

  // stage Q tile (zero-masked tail), swizzled
  {
    int qi = qt * 64 + srow;
#pragma unroll
    for (int p = 0; p < 4; ++p) {
      int slot = 4 * p + sfq;
      float4 val = make_float4(0.f, 0.f, 0.f, 0.f);
      if (qi < L) val = *(const float4*)(qg + (tokbase + qi) * 64 + slot * 4);
      *(float4*)&Qs[SWZ(srow, slot)] = val;
    }
  }

  float m[4], l[4], oa[4][4];
#pragma unroll
  for (int r = 0; r < 4; ++r) {
    m[r] = -1e30f; l[r] = 0.f;
#pragma unroll
    for (int u = 0; u < 4; ++u) oa[r][u] = 0.f;
  }

  float4 pk[4], pv[4];
  auto loadKV = [&](int ch) {
    int tk = ch * 64 + srow;
#pragma unroll
    for (int p = 0; p < 4; ++p) {
      if (tk < L) {
        long a = (tokbase + tk) * 64 + (4 * p + sfq) * 4;
        pk[p] = *(const float4*)(kg + a);
        pv[p] = *(const float4*)(vg + a);
      } else {
        pk[p] = make_float4(0.f, 0.f, 0.f, 0.f);
        pv[p] = make_float4(0.f, 0.f, 0.f, 0.f);
      }
    }
  };
  loadKV(0);

  for (int ch = 0; ch < NCH; ++ch) {
    __syncthreads();  // previous chunk's readers done
#pragma unroll
    for (int p = 0; p < 4; ++p) {
      int slot = 4 * p + sfq;
      *(float4*)&Ks[SWZ(srow, slot)] = pk[p];
      *(float4*)&Vs[SWZ(srow, slot)] = pv[p];
    }
    __syncthreads();
    if (ch + 1 < NCH) loadKV(ch + 1);  // prefetch next chunk into regs

    // S = Q K^T   (thread keys: kgr + 16u)
    float s[4][4];
#pragma unroll
    for (int r = 0; r < 4; ++r)
#pragma unroll
      for (int u = 0; u < 4; ++u) s[r][u] = 0.f;

#pragma unroll 4
    for (int cg = 0; cg < 16; ++cg) {
      float qv[4][4], kv[4][4];
#pragma unroll
      for (int r = 0; r < 4; ++r) {
        float4 q4 = *(const float4*)&Qs[SWZ(qi4 + r, cg)];
        qv[r][0] = q4.x; qv[r][1] = q4.y; qv[r][2] = q4.z; qv[r][3] = q4.w;
      }
#pragma unroll
      for (int u = 0; u < 4; ++u) {
        float4 k4 = *(const float4*)&Ks[SWZ(kgr + 16 * u, cg)];
        kv[u][0] = k4.x; kv[u][1] = k4.y; kv[u][2] = k4.z; kv[u][3] = k4.w;
      }
#pragma unroll
      for (int r = 0; r < 4; ++r)
#pragma unroll
        for (int u = 0; u < 4; ++u) {
          float a = s[r][u];
          a = fmaf(qv[r][0], kv[u][0], a);
          a = fmaf(qv[r][1], kv[u][1], a);
          a = fmaf(qv[r][2], kv[u][2], a);
          a = fmaf(qv[r][3], kv[u][3], a);
          s[r][u] = a;
        }
    }
    // scale + key mask (key index = ch*64 + kgr + 16u)
#pragma unroll
    for (int u = 0; u < 4; ++u) {
      int kidx = ch * 64 + kgr + 16 * u;
#pragma unroll
      for (int r = 0; r < 4; ++r)
        s[r][u] = (kidx < L) ? s[r][u] * 0.125f : -1e30f;
    }
    // online softmax (row = 16 consecutive lanes cover keys 0..63)
    float red[4];
#pragma unroll
    for (int r = 0; r < 4; ++r)
      red[r] = fmaxf(fmaxf(s[r][0], s[r][1]), fmaxf(s[r][2], s[r][3]));
#pragma unroll
    for (int d = 1; d < 16; d <<= 1)
#pragma unroll
      for (int r = 0; r < 4; ++r)
        red[r] = fmaxf(red[r], __shfl_xor(red[r], d));
    float fs[4];
#pragma unroll
    for (int r = 0; r < 4; ++r) {
      float mn = fmaxf(m[r], red[r]);
      fs[r] = __expf(m[r] - mn);
      m[r] = mn;
      float rs = 0.f;
#pragma unroll
      for (int u = 0; u < 4; ++u) {
        float p = __expf(s[r][u] - mn);
        s[r][u] = p;
        rs += p;
      }
      red[r] = rs;
#pragma unroll
      for (int u = 0; u < 4; ++u) oa[r][u] *= fs[r];
    }
#pragma unroll
    for (int d = 1; d < 16; d <<= 1)
#pragma unroll
      for (int r = 0; r < 4; ++r) red[r] += __shfl_xor(red[r], d);
#pragma unroll
    for (int r = 0; r < 4; ++r) l[r] = l[r] * fs[r] + red[r];

    // write P transposed: Ps[key][query]; key rows kgr+16u, query slot ogr
#pragma unroll
    for (int u = 0; u < 4; ++u)
      *(float4*)&Ps[SWZ(kgr + 16 * u, ogr)] =
          make_float4(s[0][u], s[1][u], s[2][u], s[3][u]);
    __syncthreads();

    // O += P V  (kj4 here = channel group, independent of key mapping)
#pragma unroll 4
    for (int j = 0; j < 64; ++j) {
      float4 p4 = *(const float4*)&Ps[SWZ(j, ogr)];
      float4 v4 = *(const float4*)&Vs[SWZ(j, kgr)];
      float pr[4] = {p4.x, p4.y, p4.z, p4.w};
      float vr[4] = {v4.x, v4.y, v4.z, v4.w};
#pragma unroll
      for (int r = 0; r < 4; ++r)
#pragma unroll
        for (int u = 0; u < 4; ++u)
          oa[r][u] = fmaf(pr[r], vr[u], oa[r][u]);
    }
  }

  // store O (token-major)
#pragma unroll
  for (int r = 0; r < 4; ++r) {
    int qi = qt * 64 + qi4 + r;
    if (qi < L) {
      float inv = 1.0f / l[r];
      *(float4*)(og_ + (tokbase + qi) * 64 + kj4) =
          make_float4(oa[r][0] * inv, oa[r][1] * inv, oa[r][2] * inv,
                      oa[r][3] * inv);
    }
  }
}

// ---------------------------------------------------------------------------
// Kernel 4: mask_fusion1 -> res conv -> mask_fusion2 -> fus conv.
// ---------------------------------------------------------------------------
__global__ __launch_bounds__(256) void k_fuse(
    const float* __restrict__ x, const float* __restrict__ ex,
    const float* __restrict__ att, const float* __restrict__ res_w,
    const float* __restrict__ res_b, const float* __restrict__ fus_w,
    const float* __restrict__ fus_b, const float* __restrict__ m1aw,
    const float* __restrict__ m1ab, const float* __restrict__ m1bw,
    const float* __restrict__ m1bb, const float* __restrict__ m2aw,
    const float* __restrict__ m2ab, const float* __restrict__ m2bw,
    const float* __restrict__ m2bb, float* __restrict__ out) {
  __shared__ float fT[192][68];
  const int tid = threadIdx.x;
  const int posb = blockIdx.x * 64;
  const int n = posb / HW;
  const int posn = posb % HW;

  // ---- phase A: mask fusion 1 per position; wave handles 16 positions ----
  {
    const int wv = tid >> 6, lane = tid & 63;
    float w1a0 = m1aw[0], w1a1 = m1aw[1], w1a2 = m1aw[2], w1a3 = m1aw[3];
    float b1a0 = m1ab[0], b1a1 = m1ab[1];
    float w1b0 = m1bw[0], w1b1 = m1bw[1], w1b2 = m1bw[2], w1b3 = m1bw[3];
    float b1b0 = m1bb[0], b1b1 = m1bb[1];
    for (int pp = 0; pp < 16; ++pp) {
      int pl = wv * 16 + pp;
      int pos = posn + pl;
      int h = pos / CW, wcol = pos % CW;
      auto tok = [&](int S, int W) -> int {
        int wr = h / S, kx = h % S, wcq = wcol / S, ky = wcol % S;
        return kx * (S * W * W) + ky * (W * W) + wr * W + wcq;
      };
      int j0 = tok(36, 2), j1 = tok(18, 4), j2 = tok(12, 6);
      long t0 = ((long)n * HW + j0) * 64 + lane;
      long t1 = ((long)NPOS + (long)n * HW + j1) * 64 + lane;
      long t2 = (2L * NPOS + (long)n * HW + j2) * 64 + lane;
      float av0 = att[t0], av1 = att[t1], av2 = att[t2];
      float ev0 = ex[t0], ev1 = ex[t1], ev2 = ex[t2];
      float mxa = fmaxf(fmaxf(av0, av1), av2), sma = av0 + av1 + av2;
      float mxe = fmaxf(fmaxf(ev0, ev1), ev2), sme = ev0 + ev1 + ev2;
#pragma unroll
      for (int d = 1; d < 64; d <<= 1) {
        mxa = fmaxf(mxa, __shfl_xor(mxa, d));
        sma += __shfl_xor(sma, d);
        mxe = fmaxf(mxe, __shfl_xor(mxe, d));
        sme += __shfl_xor(sme, d);
      }
      float mna = sma * (1.f / 192.f), mne = sme * (1.f / 192.f);
      float ca0 = fmaf(w1a0, mxa, fmaf(w1a1, mna, b1a0));
      float ca1 = fmaf(w1a2, mxa, fmaf(w1a3, mna, b1a1));
      float cb0 = fmaf(w1b0, mxe, fmaf(w1b1, mne, b1b0));
      float cb1 = fmaf(w1b2, mxe, fmaf(w1b3, mne, b1b1));
      bool mk = (ca0 * cb0 + ca1 * cb1) > 0.f;
      fT[lane][pl] = mk ? ev0 : av0;
      fT[64 + lane][pl] = mk ? ev1 : av1;
      fT[128 + lane][pl] = mk ? ev2 : av2;
    }
  }
  __syncthreads();

  // ---- phase B: res conv GEMM (192 -> 64), thread tile 4 outs x 4 pos ----
  const int ogi = tid & 15, pgi = tid >> 4;
  const int o4 = ogi * 4, p4 = pgi * 4;
  float acc[4][4];
#pragma unroll
  for (int i = 0; i < 4; ++i) {
    float b = res_b[o4 + i];
#pragma unroll
    for (int jj = 0; jj < 4; ++jj) acc[i][jj] = b;
  }
#pragma unroll 2
  for (int cg = 0; cg < 48; ++cg) {
    int cc = cg * 4;
    float wv4[4][4], fv4[4][4];
#pragma unroll
    for (int i = 0; i < 4; ++i) {
      float4 w4 = *(const float4*)(res_w + (o4 + i) * 192 + cc);
      wv4[i][0] = w4.x; wv4[i][1] = w4.y; wv4[i][2] = w4.z; wv4[i][3] = w4.w;
    }
#pragma unroll
    for (int u = 0; u < 4; ++u) {
      float4 f4 = *(const float4*)&fT[cc + u][p4];
      fv4[u][0] = f4.x; fv4[u][1] = f4.y; fv4[u][2] = f4.z; fv4[u][3] = f4.w;
    }
#pragma unroll
    for (int i = 0; i < 4; ++i)
#pragma unroll
      for (int jj = 0; jj < 4; ++jj) {
        float a = acc[i][jj];
        a = fmaf(wv4[i][0], fv4[0][jj], a);
        a = fmaf(wv4[i][1], fv4[1][jj], a);
        a = fmaf(wv4[i][2], fv4[2][jj], a);
        a = fmaf(wv4[i][3], fv4[3][jj], a);
        acc[i][jj] = a;
      }
  }

  // ---- phase C: mask fusion 2 ----
  float rmx[4], rsm[4];
#pragma unroll
  for (int jj = 0; jj < 4; ++jj) {
    rmx[jj] = fmaxf(fmaxf(acc[0][jj], acc[1][jj]), fmaxf(acc[2][jj], acc[3][jj]));
    rsm[jj] = acc[0][jj] + acc[1][jj] + acc[2][jj] + acc[3][jj];
  }
#pragma unroll
  for (int d = 1; d < 16; d <<= 1)
#pragma unroll
    for (int jj = 0; jj < 4; ++jj) {
      rmx[jj] = fmaxf(rmx[jj], __shfl_xor(rmx[jj], d));
      rsm[jj] += __shfl_xor(rsm[jj], d);
    }
  const float* xp = x + (long)n * CC * HW + posn;
  float xv[4][4];
#pragma unroll
  for (int i = 0; i < 4; ++i)
#pragma unroll
    for (int jj = 0; jj < 4; ++jj)
      xv[i][jj] = xp[(o4 + i) * HW + p4 + jj];
  float xmx[4], xsm[4];
#pragma unroll
  for (int jj = 0; jj < 4; ++jj) {
    xmx[jj] = fmaxf(fmaxf(xv[0][jj], xv[1][jj]), fmaxf(xv[2][jj], xv[3][jj]));
    xsm[jj] = xv[0][jj] + xv[1][jj] + xv[2][jj] + xv[3][jj];
  }
#pragma unroll
  for (int d = 1; d < 16; d <<= 1)
#pragma unroll
    for (int jj = 0; jj < 4; ++jj) {
      xmx[jj] = fmaxf(xmx[jj], __shfl_xor(xmx[jj], d));
      xsm[jj] += __shfl_xor(xsm[jj], d);
    }
  float w2a0 = m2aw[0], w2a1 = m2aw[1], w2a2 = m2aw[2], w2a3 = m2aw[3];
  float b2a0 = m2ab[0], b2a1 = m2ab[1];
  float w2b0 = m2bw[0], w2b1 = m2bw[1], w2b2 = m2bw[2], w2b3 = m2bw[3];
  float b2b0 = m2bb[0], b2b1 = m2bb[1];
  bool mk2[4];
#pragma unroll
  for (int jj = 0; jj < 4; ++jj) {
    float rmn = rsm[jj] * (1.f / 64.f), xmn = xsm[jj] * (1.f / 64.f);
    float ca0 = fmaf(w2a0, rmx[jj], fmaf(w2a1, rmn, b2a0));
    float ca1 = fmaf(w2a2, rmx[jj], fmaf(w2a3, rmn, b2a1));
    float cb0 = fmaf(w2b0, xmx[jj], fmaf(w2b1, xmn, b2b0));
    float cb1 = fmaf(w2b2, xmx[jj], fmaf(w2b3, xmn, b2b1));
    mk2[jj] = (ca0 * cb0 + ca1 * cb1) > 0.f;
  }
  __syncthreads();
#pragma unroll
  for (int i = 0; i < 4; ++i)
#pragma unroll
    for (int jj = 0; jj < 4; ++jj)
      fT[o4 + i][p4 + jj] = mk2[jj] ? xv[i][jj] : acc[i][jj];
  __syncthreads();

  // ---- phase D: fus conv GEMM (64 -> 64) + store ----
  float a2[4][4];
#pragma unroll
  for (int i = 0; i < 4; ++i) {
    float b = fus_b[o4 + i];
#pragma unroll
    for (int jj = 0; jj < 4; ++jj) a2[i][jj] = b;
  }
#pragma unroll 2
  for (int cg = 0; cg < 16; ++cg) {
    int cc = cg * 4;
    float wv4[4][4], fv4[4][4];
#pragma unroll
    for (int i = 0; i < 4; ++i) {
      float4 w4 = *(const float4*)(fus_w + (o4 + i) * 64 + cc);
      wv4[i][0] = w4.x; wv4[i][1] = w4.y; wv4[i][2] = w4.z; wv4[i][3] = w4.w;
    }
#pragma unroll
    for (int u = 0; u < 4; ++u) {
      float4 f4 = *(const float4*)&fT[cc + u][p4];
      fv4[u][0] = f4.x; fv4[u][1] = f4.y; fv4[u][2] = f4.z; fv4[u][3] = f4.w;
    }
#pragma unroll
    for (int i = 0; i < 4; ++i)
#pragma unroll
      for (int jj = 0; jj < 4; ++jj) {
        float a = a2[i][jj];
        a = fmaf(wv4[i][0], fv4[0][jj], a);
        a = fmaf(wv4[i][1], fv4[1][jj], a);
        a = fmaf(wv4[i][2], fv4[2][jj], a);
        a = fmaf(wv4[i][3], fv4[3][jj], a);
        a2[i][jj] = a;
      }
  }
#pragma unroll
  for (int i = 0; i < 4; ++i)
    *(float4*)(out + ((long)n * CC + o4 + i) * HW + posn + p4) =
        make_float4(a2[i][0], a2[i][1], a2[i][2], a2[i][3]);
}

// ---------------------------------------------------------------------------
extern "C" void kernel_launch(void* const* d_in, const int* in_sizes, int n_in,
                              void* d_out, int out_size, void* d_ws,
                              size_t ws_size, hipStream_t stream) {
  (void)in_sizes; (void)n_in; (void)out_size;
  const float* x      = (const float*)d_in[0];
  const float* exp_w  = (const float*)d_in[1];
  const float* exp_b  = (const float*)d_in[2];
  const float* res_w  = (const float*)d_in[3];
  const float* res_b  = (const float*)d_in[4];
  const float* fus_w  = (const float*)d_in[5];
  const float* fus_b  = (const float*)d_in[6];
  const float* wq     = (const float*)d_in[7];
  const float* wk     = (const float*)d_in[8];
  const float* wv     = (const float*)d_in[9];
  const float* m1aw   = (const float*)d_in[10];
  const float* m1ab   = (const float*)d_in[11];
  const float* m1bw   = (const float*)d_in[12];
  const float* m1bb   = (const float*)d_in[13];
  const float* m2aw   = (const float*)d_in[14];
  const float* m2ab   = (const float*)d_in[15];
  const float* m2bw   = (const float*)d_in[16];
  const float* m2bb   = (const float*)d_in[17];

  const size_t needF = 5 * (size_t)TOKF + 3 * 4096;
  if (ws_size < needF * sizeof(float)) return;
  float* ws = (float*)d_ws;
  float* ex = ws;
  float* qb = ex + TOKF;
  float* kb = qb + TOKF;
  float* vb = kb + TOKF;
  float* ob = vb + TOKF;
  float* wT = ob + TOKF;

  k_prep<<<291, 256, 0, stream>>>(x, exp_w, exp_b, wq, wk, wv, ex, wT);
  k_qkv<<<972, 256, 0, stream>>>(ex, wT, qb, kb, vb);
  k_attn<<<1152, 256, 0, stream>>>(qb, kb, vb, ob);
  k_fuse<<<324, 256, 0, stream>>>(x, ex, ob, res_w, res_b, fus_w, fus_b, m1aw,
                                  m1ab, m1bw, m1bb, m2aw, m2ab, m2bw, m2bb,
                                  (float*)d_out);
}

// Round 4
// 227.539 us; speedup vs baseline: 2.9255x; 1.6382x over previous
//
#include <hip/hip_runtime.h>

constexpr int CN = 4;          // batch
constexpr int CC = 64;         // channels per window
constexpr int CH = 72, CW = 72;
constexpr int HW = CH * CW;    // 5184
constexpr int NPOS = CN * HW;  // 20736 tokens per window
constexpr long TOKF = 3L * NPOS * 64;  // floats in one [3][NPOS][64] array

typedef _Float16 h4 __attribute__((ext_vector_type(4)));
typedef _Float16 h8 __attribute__((ext_vector_type(8)));
typedef float f4 __attribute__((ext_vector_type(4)));

// float4-slot XOR swizzle for [rows][64] fp32 LDS arrays (16 slots/row).
#define SWZ(row, slot) (((row) << 6) + ((((slot) ^ ((row) & 15))) << 2))

// f16 [row][64] arrays: 8 granules of 8 f16 per row; swizzle granule by row&7.
__device__ __forceinline__ int fidx(int row, int g, int off) {
  return (row << 6) + ((g ^ (row & 7)) << 3) + off;
}

// ---------------------------------------------------------------------------
// Kernel 1: expand conv (3 windows) + wq/wk/wv transpose, one launch.
// ---------------------------------------------------------------------------
template <int WW, int SS>
__device__ __forceinline__ void expand_body(const float* __restrict__ x,
                                            const float* __restrict__ w64,
                                            const float* __restrict__ b64,
                                            float* __restrict__ out, int pg) {
  int n = pg / HW;
  int pos = pg - n * HW;
  int h = pos / CW, wcol = pos % CW;

  float xv[64];
  const float* xp = x + (long)n * CC * HW + pos;
#pragma unroll
  for (int c = 0; c < 64; ++c) xv[c] = xp[c * HW];

  int wr = h / SS, kx = h % SS, wcq = wcol / SS, ky = wcol % SS;
  int j = kx * (SS * WW * WW) + ky * (WW * WW) + wr * WW + wcq;
  float* op = out + ((long)n * HW + j) * 64;

#pragma unroll 1
  for (int og = 0; og < 16; ++og) {
    float t0[4];
#pragma unroll
    for (int i = 0; i < 4; ++i) {
      int o = og * 4 + i;
      float acc = b64[o];
      const float* wp = w64 + o * 64;
#pragma unroll
      for (int cg = 0; cg < 16; ++cg) {
        float4 w4 = *(const float4*)(wp + 4 * cg);
        acc = fmaf(xv[4 * cg + 0], w4.x, acc);
        acc = fmaf(xv[4 * cg + 1], w4.y, acc);
        acc = fmaf(xv[4 * cg + 2], w4.z, acc);
        acc = fmaf(xv[4 * cg + 3], w4.w, acc);
      }
      t0[i] = acc;
    }
    *(float4*)(op + og * 4) = make_float4(t0[0], t0[1], t0[2], t0[3]);
  }
}

__global__ __launch_bounds__(256) void k_prep(
    const float* __restrict__ x, const float* __restrict__ exp_w,
    const float* __restrict__ exp_b, const float* __restrict__ wq,
    const float* __restrict__ wk, const float* __restrict__ wv,
    float* __restrict__ ex, float* __restrict__ wT) {
  int b = blockIdx.x;
  if (b >= 243) {  // transpose part
    int i = (b - 243) * 256 + threadIdx.x;  // [0, 12288)
    int m = i >> 12;
    int r = i & 4095;
    int cp = r >> 6, c = r & 63;
    const float* src = (m == 0) ? wq : ((m == 1) ? wk : wv);
    wT[i] = src[c * 64 + cp];
    return;
  }
  int wi = b / 81;
  int pg = (b - wi * 81) * 256 + threadIdx.x;  // [0, NPOS)
  if (wi == 0)
    expand_body<2, 36>(x, exp_w, exp_b, ex, pg);
  else if (wi == 1)
    expand_body<4, 18>(x, exp_w + 4096, exp_b + 64, ex + (long)NPOS * 64, pg);
  else
    expand_body<6, 12>(x, exp_w + 8192, exp_b + 128, ex + 2L * NPOS * 64, pg);
}

// ---------------------------------------------------------------------------
// Kernel 2: q/k/v projections as LDS-tiled GEMM.
// ---------------------------------------------------------------------------
__global__ __launch_bounds__(256) void k_qkv(const float* __restrict__ ex,
                                             const float* __restrict__ wT,
                                             float* __restrict__ q,
                                             float* __restrict__ k,
                                             float* __restrict__ v) {
  __shared__ float Es[4096];    // 64 tokens x 64 ch, swizzled
  __shared__ float wls[12288];  // 192 rows x 64 ch, swizzled

  const int tid = threadIdx.x;
  const long tok0 = (long)blockIdx.x * 64;
  const int srow = tid >> 2, sfq = tid & 3;

#pragma unroll
  for (int p = 0; p < 4; ++p) {
    int slot = 4 * p + sfq;
    float4 val = *(const float4*)(ex + (tok0 + srow) * 64 + slot * 4);
    *(float4*)&Es[SWZ(srow, slot)] = val;
  }
#pragma unroll
  for (int it = 0; it < 12; ++it) {
    int i = it * 256 + tid;  // [0, 3072) float4 index
    int row = i >> 4, slot = i & 15;
    *(float4*)&wls[SWZ(row, slot)] = ((const float4*)wT)[i];
  }
  __syncthreads();

  const int og = tid & 15, tg = tid >> 4;
  const int o4 = og * 4, t4 = tg * 4;

#pragma unroll 1
  for (int pj = 0; pj < 3; ++pj) {
    float acc[4][4];
#pragma unroll
    for (int i = 0; i < 4; ++i)
#pragma unroll
      for (int jj = 0; jj < 4; ++jj) acc[i][jj] = 0.f;

#pragma unroll 4
    for (int cg = 0; cg < 16; ++cg) {
      float wv4[4][4], ev4[4][4];
#pragma unroll
      for (int i = 0; i < 4; ++i) {
        float4 w4 = *(const float4*)&wls[SWZ(pj * 64 + o4 + i, cg)];
        wv4[i][0] = w4.x; wv4[i][1] = w4.y; wv4[i][2] = w4.z; wv4[i][3] = w4.w;
      }
#pragma unroll
      for (int jj = 0; jj < 4; ++jj) {
        float4 e4 = *(const float4*)&Es[SWZ(t4 + jj, cg)];
        ev4[jj][0] = e4.x; ev4[jj][1] = e4.y; ev4[jj][2] = e4.z; ev4[jj][3] = e4.w;
      }
#pragma unroll
      for (int i = 0; i < 4; ++i)
#pragma unroll
        for (int jj = 0; jj < 4; ++jj) {
          float a = acc[i][jj];
          a = fmaf(wv4[i][0], ev4[jj][0], a);
          a = fmaf(wv4[i][1], ev4[jj][1], a);
          a = fmaf(wv4[i][2], ev4[jj][2], a);
          a = fmaf(wv4[i][3], ev4[jj][3], a);
          acc[i][jj] = a;
        }
    }
    float* op = (pj == 0 ? q : (pj == 1 ? k : v));
#pragma unroll
    for (int jj = 0; jj < 4; ++jj)
      *(float4*)(op + (tok0 + t4 + jj) * 64 + o4) =
          make_float4(acc[0][jj], acc[1][jj], acc[2][jj], acc[3][jj]);
  }
}

// ---------------------------------------------------------------------------
// Kernel 3: merged MFMA attention (fp16 hi/lo 3-term split, fp32-equivalent).
// Per block: 64-query tile. Per wave: 16-query strip. S^T = K*Q^T so softmax
// is lane-local per q; P is wave-private in LDS [q][key] (A-operand layout).
// ---------------------------------------------------------------------------
__global__ __launch_bounds__(256) void k_attn(const float* __restrict__ qg,
                                              const float* __restrict__ kg,
                                              const float* __restrict__ vg,
                                              float* __restrict__ og_) {
  __shared__ __align__(16) _Float16 Qh[4096], Ql[4096];
  __shared__ __align__(16) _Float16 Kh[4096], Kl[4096];
  __shared__ __align__(16) _Float16 Vth[4096], Vtl[4096];  // V^T [ch][key]
  __shared__ __align__(16) _Float16 Ph[4096], Pl[4096];    // P  [q][key]

  const int tid = threadIdx.x;
  int b = blockIdx.x;
  int L, g, qt, NCH;
  long tokbase;
  if (b < 336) {
    L = 1296; NCH = 21; g = b / 21; qt = b - g * 21;
    tokbase = (long)g * 1296;
  } else if (b < 720) {
    int t = b - 336;
    L = 324; NCH = 6; g = t / 6; qt = t - g * 6;
    tokbase = (long)NPOS + (long)g * 324;
  } else {
    int t = b - 720;
    L = 144; NCH = 3; g = t / 3; qt = t - g * 3;
    tokbase = 2L * NPOS + (long)g * 144;
  }

  const int lane = tid & 63, w = tid >> 6;
  const int lw = lane & 15, lg = lane >> 4;
  const int w16 = w * 16;
  const int srow = tid >> 2;  // staging row 0..63
  const int sfq = tid & 3;

  // ---- stage Q once: scaled by 0.125*log2(e), split hi/lo ----
  {
    const float SC = 0.125f * 1.4426950408889634f;
    int qi = qt * 64 + srow;
#pragma unroll
    for (int p = 0; p < 4; ++p) {
      int ch0 = (sfq + 4 * p) * 4;
      float4 val = make_float4(0.f, 0.f, 0.f, 0.f);
      if (qi < L) val = *(const float4*)(qg + (tokbase + qi) * 64 + ch0);
      val.x *= SC; val.y *= SC; val.z *= SC; val.w *= SC;
      h4 hh = {(_Float16)val.x, (_Float16)val.y, (_Float16)val.z,
               (_Float16)val.w};
      h4 ll = {(_Float16)(val.x - (float)hh[0]),
               (_Float16)(val.y - (float)hh[1]),
               (_Float16)(val.z - (float)hh[2]),
               (_Float16)(val.w - (float)hh[3])};
      int gr = ch0 >> 3, off = ch0 & 7;
      *(h4*)&Qh[fidx(srow, gr, off)] = hh;
      *(h4*)&Ql[fidx(srow, gr, off)] = ll;
    }
  }

  float m_s = -1e30f, l_s = 0.f;
  f4 oa[4];
#pragma unroll
  for (int i = 0; i < 4; ++i) oa[i] = (f4){0.f, 0.f, 0.f, 0.f};

  float4 pk[4], pv[4];
  auto loadKV = [&](int chn) {
    int tk = chn * 64 + srow;
#pragma unroll
    for (int p = 0; p < 4; ++p) {
      if (tk < L) {
        long a = (tokbase + tk) * 64 + (4 * p + sfq) * 4;
        pk[p] = *(const float4*)(kg + a);
        pv[p] = *(const float4*)(vg + a);
      } else {
        pk[p] = make_float4(0.f, 0.f, 0.f, 0.f);
        pv[p] = make_float4(0.f, 0.f, 0.f, 0.f);
      }
    }
  };
  loadKV(0);

  for (int ch = 0; ch < NCH; ++ch) {
    __syncthreads();  // previous chunk's readers done
    // ---- stage K [key][ch] and V^T [ch][key], both split hi/lo ----
#pragma unroll
    for (int p = 0; p < 4; ++p) {
      int ch0 = (sfq + 4 * p) * 4;
      int gr = ch0 >> 3, off = ch0 & 7;
      {
        float4 kv = pk[p];
        h4 hh = {(_Float16)kv.x, (_Float16)kv.y, (_Float16)kv.z,
                 (_Float16)kv.w};
        h4 ll = {(_Float16)(kv.x - (float)hh[0]),
                 (_Float16)(kv.y - (float)hh[1]),
                 (_Float16)(kv.z - (float)hh[2]),
                 (_Float16)(kv.w - (float)hh[3])};
        *(h4*)&Kh[fidx(srow, gr, off)] = hh;
        *(h4*)&Kl[fidx(srow, gr, off)] = ll;
      }
      {
        float4 vv = pv[p];
        int kgr = srow >> 3, ko = srow & 7;
        _Float16 a0 = (_Float16)vv.x;
        Vth[fidx(ch0 + 0, kgr, ko)] = a0;
        Vtl[fidx(ch0 + 0, kgr, ko)] = (_Float16)(vv.x - (float)a0);
        _Float16 a1 = (_Float16)vv.y;
        Vth[fidx(ch0 + 1, kgr, ko)] = a1;
        Vtl[fidx(ch0 + 1, kgr, ko)] = (_Float16)(vv.y - (float)a1);
        _Float16 a2 = (_Float16)vv.z;
        Vth[fidx(ch0 + 2, kgr, ko)] = a2;
        Vtl[fidx(ch0 + 2, kgr, ko)] = (_Float16)(vv.z - (float)a2);
        _Float16 a3 = (_Float16)vv.w;
        Vth[fidx(ch0 + 3, kgr, ko)] = a3;
        Vtl[fidx(ch0 + 3, kgr, ko)] = (_Float16)(vv.w - (float)a3);
      }
    }
    __syncthreads();
    if (ch + 1 < NCH) loadKV(ch + 1);  // prefetch next chunk into regs

    // ---- S^T = K * Q^T  (tile rows = keys, cols = wave's 16 queries) ----
    f4 sa[4];
#pragma unroll
    for (int kt = 0; kt < 4; ++kt) sa[kt] = (f4){0.f, 0.f, 0.f, 0.f};
#pragma unroll
    for (int slab = 0; slab < 2; ++slab) {
      h8 qbh = *(const h8*)&Qh[fidx(w16 + lw, slab * 4 + lg, 0)];
      h8 qbl = *(const h8*)&Ql[fidx(w16 + lw, slab * 4 + lg, 0)];
#pragma unroll
      for (int kt = 0; kt < 4; ++kt) {
        h8 ah = *(const h8*)&Kh[fidx(kt * 16 + lw, slab * 4 + lg, 0)];
        h8 al = *(const h8*)&Kl[fidx(kt * 16 + lw, slab * 4 + lg, 0)];
        sa[kt] = __builtin_amdgcn_mfma_f32_16x16x32_f16(ah, qbh, sa[kt], 0, 0, 0);
        sa[kt] = __builtin_amdgcn_mfma_f32_16x16x32_f16(al, qbh, sa[kt], 0, 0, 0);
        sa[kt] = __builtin_amdgcn_mfma_f32_16x16x32_f16(ah, qbl, sa[kt], 0, 0, 0);
      }
    }

    // ---- online softmax (exp2 domain); lane owns q = w16+lw ----
    float pr[4][4];
    float pmax = -1e30f;
#pragma unroll
    for (int kt = 0; kt < 4; ++kt)
#pragma unroll
      for (int r = 0; r < 4; ++r) {
        int kidx = ch * 64 + kt * 16 + 4 * lg + r;
        float s = (kidx < L) ? sa[kt][r] : -1e30f;
        pr[kt][r] = s;
        pmax = fmaxf(pmax, s);
      }
    pmax = fmaxf(pmax, __shfl_xor(pmax, 16));
    pmax = fmaxf(pmax, __shfl_xor(pmax, 32));
    float mn = fmaxf(m_s, pmax);
    float fs = exp2f(m_s - mn);
    m_s = mn;
    float rs = 0.f;
#pragma unroll
    for (int kt = 0; kt < 4; ++kt)
#pragma unroll
      for (int r = 0; r < 4; ++r) {
        float e = exp2f(pr[kt][r] - mn);
        pr[kt][r] = e;
        rs += e;
      }
    rs += __shfl_xor(rs, 16);
    rs += __shfl_xor(rs, 32);
    l_s = l_s * fs + rs;
    // rescale O (O rows live at q = w16 + 4*lg + r)
    float fsb[4];
#pragma unroll
    for (int r = 0; r < 4; ++r) fsb[r] = __shfl(fs, 4 * lg + r);
#pragma unroll
    for (int ct = 0; ct < 4; ++ct)
#pragma unroll
      for (int r = 0; r < 4; ++r) oa[ct][r] *= fsb[r];

    // ---- store P [q][key] hi/lo (wave-private rows; no barrier needed) ----
#pragma unroll
    for (int kt = 0; kt < 4; ++kt) {
      h4 hh = {(_Float16)pr[kt][0], (_Float16)pr[kt][1], (_Float16)pr[kt][2],
               (_Float16)pr[kt][3]};
      h4 ll = {(_Float16)(pr[kt][0] - (float)hh[0]),
               (_Float16)(pr[kt][1] - (float)hh[1]),
               (_Float16)(pr[kt][2] - (float)hh[2]),
               (_Float16)(pr[kt][3] - (float)hh[3])};
      int key0 = kt * 16 + 4 * lg;
      int kgr = key0 >> 3, ko = key0 & 7;
      *(h4*)&Ph[fidx(w16 + lw, kgr, ko)] = hh;
      *(h4*)&Pl[fidx(w16 + lw, kgr, ko)] = ll;
    }

    // ---- O += P * V ----
#pragma unroll
    for (int slab = 0; slab < 2; ++slab) {
      h8 pah = *(const h8*)&Ph[fidx(w16 + lw, slab * 4 + lg, 0)];
      h8 pal = *(const h8*)&Pl[fidx(w16 + lw, slab * 4 + lg, 0)];
#pragma unroll
      for (int ct = 0; ct < 4; ++ct) {
        h8 vbh = *(const h8*)&Vth[fidx(ct * 16 + lw, slab * 4 + lg, 0)];
        h8 vbl = *(const h8*)&Vtl[fidx(ct * 16 + lw, slab * 4 + lg, 0)];
        oa[ct] = __builtin_amdgcn_mfma_f32_16x16x32_f16(pah, vbh, oa[ct], 0, 0, 0);
        oa[ct] = __builtin_amdgcn_mfma_f32_16x16x32_f16(pal, vbh, oa[ct], 0, 0, 0);
        oa[ct] = __builtin_amdgcn_mfma_f32_16x16x32_f16(pah, vbl, oa[ct], 0, 0, 0);
      }
    }
  }

  // ---- store O: q = qt*64 + w16 + 4*lg + r ; ch = ct*16 + lw ----
  float linv[4];
#pragma unroll
  for (int r = 0; r < 4; ++r) linv[r] = 1.0f / __shfl(l_s, 4 * lg + r);
#pragma unroll
  for (int r = 0; r < 4; ++r) {
    int qi = qt * 64 + w16 + 4 * lg + r;
    if (qi < L) {
      float* op = og_ + (tokbase + qi) * 64 + lw;
#pragma unroll
      for (int ct = 0; ct < 4; ++ct) op[ct * 16] = oa[ct][r] * linv[r];
    }
  }
}

// ---------------------------------------------------------------------------
// Kernel 4: mask_fusion1 -> res conv -> mask_fusion2 -> fus conv.
// ---------------------------------------------------------------------------
__global__ __launch_bounds__(256) void k_fuse(
    const float* __restrict__ x, const float* __restrict__ ex,
    const float* __restrict__ att, const float* __restrict__ res_w,
    const float* __restrict__ res_b, const float* __restrict__ fus_w,
    const float* __restrict__ fus_b, const float* __restrict__ m1aw,
    const float* __restrict__ m1ab, const float* __restrict__ m1bw,
    const float* __restrict__ m1bb, const float* __restrict__ m2aw,
    const float* __restrict__ m2ab, const float* __restrict__ m2bw,
    const float* __restrict__ m2bb, float* __restrict__ out) {
  __shared__ float fT[192][68];
  const int tid = threadIdx.x;
  const int posb = blockIdx.x * 64;
  const int n = posb / HW;
  const int posn = posb % HW;

  // ---- phase A: mask fusion 1 per position; wave handles 16 positions ----
  {
    const int wv = tid >> 6, lane = tid & 63;
    float w1a0 = m1aw[0], w1a1 = m1aw[1], w1a2 = m1aw[2], w1a3 = m1aw[3];
    float b1a0 = m1ab[0], b1a1 = m1ab[1];
    float w1b0 = m1bw[0], w1b1 = m1bw[1], w1b2 = m1bw[2], w1b3 = m1bw[3];
    float b1b0 = m1bb[0], b1b1 = m1bb[1];
    for (int pp = 0; pp < 16; ++pp) {
      int pl = wv * 16 + pp;
      int pos = posn + pl;
      int h = pos / CW, wcol = pos % CW;
      auto tok = [&](int S, int W) -> int {
        int wr = h / S, kx = h % S, wcq = wcol / S, ky = wcol % S;
        return kx * (S * W * W) + ky * (W * W) + wr * W + wcq;
      };
      int j0 = tok(36, 2), j1 = tok(18, 4), j2 = tok(12, 6);
      long t0 = ((long)n * HW + j0) * 64 + lane;
      long t1 = ((long)NPOS + (long)n * HW + j1) * 64 + lane;
      long t2 = (2L * NPOS + (long)n * HW + j2) * 64 + lane;
      float av0 = att[t0], av1 = att[t1], av2 = att[t2];
      float ev0 = ex[t0], ev1 = ex[t1], ev2 = ex[t2];
      float mxa = fmaxf(fmaxf(av0, av1), av2), sma = av0 + av1 + av2;
      float mxe = fmaxf(fmaxf(ev0, ev1), ev2), sme = ev0 + ev1 + ev2;
#pragma unroll
      for (int d = 1; d < 64; d <<= 1) {
        mxa = fmaxf(mxa, __shfl_xor(mxa, d));
        sma += __shfl_xor(sma, d);
        mxe = fmaxf(mxe, __shfl_xor(mxe, d));
        sme += __shfl_xor(sme, d);
      }
      float mna = sma * (1.f / 192.f), mne = sme * (1.f / 192.f);
      float ca0 = fmaf(w1a0, mxa, fmaf(w1a1, mna, b1a0));
      float ca1 = fmaf(w1a2, mxa, fmaf(w1a3, mna, b1a1));
      float cb0 = fmaf(w1b0, mxe, fmaf(w1b1, mne, b1b0));
      float cb1 = fmaf(w1b2, mxe, fmaf(w1b3, mne, b1b1));
      bool mk = (ca0 * cb0 + ca1 * cb1) > 0.f;
      fT[lane][pl] = mk ? ev0 : av0;
      fT[64 + lane][pl] = mk ? ev1 : av1;
      fT[128 + lane][pl] = mk ? ev2 : av2;
    }
  }
  __syncthreads();

  // ---- phase B: res conv GEMM (192 -> 64), thread tile 4 outs x 4 pos ----
  const int ogi = tid & 15, pgi = tid >> 4;
  const int o4 = ogi * 4, p4 = pgi * 4;
  float acc[4][4];
#pragma unroll
  for (int i = 0; i < 4; ++i) {
    float b = res_b[o4 + i];
#pragma unroll
    for (int jj = 0; jj < 4; ++jj) acc[i][jj] = b;
  }
#pragma unroll 2
  for (int cg = 0; cg < 48; ++cg) {
    int cc = cg * 4;
    float wv4[4][4], fv4[4][4];
#pragma unroll
    for (int i = 0; i < 4; ++i) {
      float4 w4 = *(const float4*)(res_w + (o4 + i) * 192 + cc);
      wv4[i][0] = w4.x; wv4[i][1] = w4.y; wv4[i][2] = w4.z; wv4[i][3] = w4.w;
    }
#pragma unroll
    for (int u = 0; u < 4; ++u) {
      float4 f4_ = *(const float4*)&fT[cc + u][p4];
      fv4[u][0] = f4_.x; fv4[u][1] = f4_.y; fv4[u][2] = f4_.z; fv4[u][3] = f4_.w;
    }
#pragma unroll
    for (int i = 0; i < 4; ++i)
#pragma unroll
      for (int jj = 0; jj < 4; ++jj) {
        float a = acc[i][jj];
        a = fmaf(wv4[i][0], fv4[0][jj], a);
        a = fmaf(wv4[i][1], fv4[1][jj], a);
        a = fmaf(wv4[i][2], fv4[2][jj], a);
        a = fmaf(wv4[i][3], fv4[3][jj], a);
        acc[i][jj] = a;
      }
  }

  // ---- phase C: mask fusion 2 ----
  float rmx[4], rsm[4];
#pragma unroll
  for (int jj = 0; jj < 4; ++jj) {
    rmx[jj] = fmaxf(fmaxf(acc[0][jj], acc[1][jj]), fmaxf(acc[2][jj], acc[3][jj]));
    rsm[jj] = acc[0][jj] + acc[1][jj] + acc[2][jj] + acc[3][jj];
  }
#pragma unroll
  for (int d = 1; d < 16; d <<= 1)
#pragma unroll
    for (int jj = 0; jj < 4; ++jj) {
      rmx[jj] = fmaxf(rmx[jj], __shfl_xor(rmx[jj], d));
      rsm[jj] += __shfl_xor(rsm[jj], d);
    }
  const float* xp = x + (long)n * CC * HW + posn;
  float xv[4][4];
#pragma unroll
  for (int i = 0; i < 4; ++i)
#pragma unroll
    for (int jj = 0; jj < 4; ++jj)
      xv[i][jj] = xp[(o4 + i) * HW + p4 + jj];
  float xmx[4], xsm[4];
#pragma unroll
  for (int jj = 0; jj < 4; ++jj) {
    xmx[jj] = fmaxf(fmaxf(xv[0][jj], xv[1][jj]), fmaxf(xv[2][jj], xv[3][jj]));
    xsm[jj] = xv[0][jj] + xv[1][jj] + xv[2][jj] + xv[3][jj];
  }
#pragma unroll
  for (int d = 1; d < 16; d <<= 1)
#pragma unroll
    for (int jj = 0; jj < 4; ++jj) {
      xmx[jj] = fmaxf(xmx[jj], __shfl_xor(xmx[jj], d));
      xsm[jj] += __shfl_xor(xsm[jj], d);
    }
  float w2a0 = m2aw[0], w2a1 = m2aw[1], w2a2 = m2aw[2], w2a3 = m2aw[3];
  float b2a0 = m2ab[0], b2a1 = m2ab[1];
  float w2b0 = m2bw[0], w2b1 = m2bw[1], w2b2 = m2bw[2], w2b3 = m2bw[3];
  float b2b0 = m2bb[0], b2b1 = m2bb[1];
  bool mk2[4];
#pragma unroll
  for (int jj = 0; jj < 4; ++jj) {
    float rmn = rsm[jj] * (1.f / 64.f), xmn = xsm[jj] * (1.f / 64.f);
    float ca0 = fmaf(w2a0, rmx[jj], fmaf(w2a1, rmn, b2a0));
    float ca1 = fmaf(w2a2, rmx[jj], fmaf(w2a3, rmn, b2a1));
    float cb0 = fmaf(w2b0, xmx[jj], fmaf(w2b1, xmn, b2b0));
    float cb1 = fmaf(w2b2, xmx[jj], fmaf(w2b3, xmn, b2b1));
    mk2[jj] = (ca0 * cb0 + ca1 * cb1) > 0.f;
  }
  __syncthreads();
#pragma unroll
  for (int i = 0; i < 4; ++i)
#pragma unroll
    for (int jj = 0; jj < 4; ++jj)
      fT[o4 + i][p4 + jj] = mk2[jj] ? xv[i][jj] : acc[i][jj];
  __syncthreads();

  // ---- phase D: fus conv GEMM (64 -> 64) + store ----
  float a2[4][4];
#pragma unroll
  for (int i = 0; i < 4; ++i) {
    float b = fus_b[o4 + i];
#pragma unroll
    for (int jj = 0; jj < 4; ++jj) a2[i][jj] = b;
  }
#pragma unroll 2
  for (int cg = 0; cg < 16; ++cg) {
    int cc = cg * 4;
    float wv4[4][4], fv4[4][4];
#pragma unroll
    for (int i = 0; i < 4; ++i) {
      float4 w4 = *(const float4*)(fus_w + (o4 + i) * 64 + cc);
      wv4[i][0] = w4.x; wv4[i][1] = w4.y; wv4[i][2] = w4.z; wv4[i][3] = w4.w;
    }
#pragma unroll
    for (int u = 0; u < 4; ++u) {
      float4 f4_ = *(const float4*)&fT[cc + u][p4];
      fv4[u][0] = f4_.x; fv4[u][1] = f4_.y; fv4[u][2] = f4_.z; fv4[u][3] = f4_.w;
    }
#pragma unroll
    for (int i = 0; i < 4; ++i)
#pragma unroll
      for (int jj = 0; jj < 4; ++jj) {
        float a = a2[i][jj];
        a = fmaf(wv4[i][0], fv4[0][jj], a);
        a = fmaf(wv4[i][1], fv4[1][jj], a);
        a = fmaf(wv4[i][2], fv4[2][jj], a);
        a = fmaf(wv4[i][3], fv4[3][jj], a);
        a2[i][jj] = a;
      }
  }
#pragma unroll
  for (int i = 0; i < 4; ++i)
    *(float4*)(out + ((long)n * CC + o4 + i) * HW + posn + p4) =
        make_float4(a2[i][0], a2[i][1], a2[i][2], a2[i][3]);
}

// ---------------------------------------------------------------------------
extern "C" void kernel_launch(void* const* d_in, const int* in_sizes, int n_in,
                              void* d_out, int out_size, void* d_ws,
                              size_t ws_size, hipStream_t stream) {
  (void)in_sizes; (void)n_in; (void)out_size;
  const float* x      = (const float*)d_in[0];
  const float* exp_w  = (const float*)d_in[1];
  const float* exp_b  = (const float*)d_in[2];
  const float* res_w  = (const float*)d_in[3];
  const float* res_b  = (const float*)d_in[4];
  const float* fus_w  = (const float*)d_in[5];
  const float* fus_b  = (const float*)d_in[6];
  const float* wq     = (const float*)d_in[7];
  const float* wk     = (const float*)d_in[8];
  const float* wv     = (const float*)d_in[9];
  const float* m1aw   = (const float*)d_in[10];
  const float* m1ab   = (const float*)d_in[11];
  const float* m1bw   = (const float*)d_in[12];
  const float* m1bb   = (const float*)d_in[13];
  const float* m2aw   = (const float*)d_in[14];
  const float* m2ab   = (const float*)d_in[15];
  const float* m2bw   = (const float*)d_in[16];
  const float* m2bb   = (const float*)d_in[17];

  const size_t needF = 5 * (size_t)TOKF + 3 * 4096;
  if (ws_size < needF * sizeof(float)) return;
  float* ws = (float*)d_ws;
  float* ex = ws;
  float* qb = ex + TOKF;
  float* kb = qb + TOKF;
  float* vb = kb + TOKF;
  float* ob = vb + TOKF;
  float* wT = ob + TOKF;

  k_prep<<<291, 256, 0, stream>>>(x, exp_w, exp_b, wq, wk, wv, ex, wT);
  k_qkv<<<972, 256, 0, stream>>>(ex, wT, qb, kb, vb);
  k_attn<<<1152, 256, 0, stream>>>(qb, kb, vb, ob);
  k_fuse<<<324, 256, 0, stream>>>(x, ex, ob, res_w, res_b, fus_w, fus_b, m1aw,
                                  m1ab, m1bw, m1bb, m2aw, m2ab, m2bw, m2bb,
                                  (float*)d_out);
}

// Round 5
// 198.748 us; speedup vs baseline: 3.3493x; 1.1449x over previous
//
#include <hip/hip_runtime.h>

constexpr int CN = 4;          // batch
constexpr int CC = 64;         // channels per window
constexpr int CH = 72, CW = 72;
constexpr int HW = CH * CW;    // 5184
constexpr int NPOS = CN * HW;  // 20736 tokens per window
constexpr long TOKF = 3L * NPOS * 64;  // elems in one [3][NPOS][64] array
constexpr long HPAD = 4096;            // tail pad (halves) for OOB-safe reads

typedef _Float16 h4 __attribute__((ext_vector_type(4)));
typedef _Float16 h8 __attribute__((ext_vector_type(8)));
typedef float f4 __attribute__((ext_vector_type(4)));

// float4-slot XOR swizzle for [rows][64] fp32 LDS arrays (16 slots/row).
#define SWZ(row, slot) (((row) << 6) + ((((slot) ^ ((row) & 15))) << 2))

// f16 [row][64] arrays: 8 granules of 8 f16 per row; swizzle granule by row&7.
__device__ __forceinline__ int fidx(int row, int g, int off) {
  return (row << 6) + ((g ^ (row & 7)) << 3) + off;
}

// ---------------------------------------------------------------------------
// Kernel 1: expand conv (3 windows) + wq/wk/wv transpose+split, one launch.
// ---------------------------------------------------------------------------
template <int WW, int SS>
__device__ __forceinline__ void expand_body(const float* __restrict__ x,
                                            const float* __restrict__ w64,
                                            const float* __restrict__ b64,
                                            float* __restrict__ out, int pg) {
  int n = pg / HW;
  int pos = pg - n * HW;
  int h = pos / CW, wcol = pos % CW;

  float xv[64];
  const float* xp = x + (long)n * CC * HW + pos;
#pragma unroll
  for (int c = 0; c < 64; ++c) xv[c] = xp[c * HW];

  int wr = h / SS, kx = h % SS, wcq = wcol / SS, ky = wcol % SS;
  int j = kx * (SS * WW * WW) + ky * (WW * WW) + wr * WW + wcq;
  float* op = out + ((long)n * HW + j) * 64;

#pragma unroll 1
  for (int og = 0; og < 16; ++og) {
    float t0[4];
#pragma unroll
    for (int i = 0; i < 4; ++i) {
      int o = og * 4 + i;
      float acc = b64[o];
      const float* wp = w64 + o * 64;
#pragma unroll
      for (int cg = 0; cg < 16; ++cg) {
        float4 w4 = *(const float4*)(wp + 4 * cg);
        acc = fmaf(xv[4 * cg + 0], w4.x, acc);
        acc = fmaf(xv[4 * cg + 1], w4.y, acc);
        acc = fmaf(xv[4 * cg + 2], w4.z, acc);
        acc = fmaf(xv[4 * cg + 3], w4.w, acc);
      }
      t0[i] = acc;
    }
    *(float4*)(op + og * 4) = make_float4(t0[0], t0[1], t0[2], t0[3]);
  }
}

__global__ __launch_bounds__(256) void k_prep(
    const float* __restrict__ x, const float* __restrict__ exp_w,
    const float* __restrict__ exp_b, const float* __restrict__ wq,
    const float* __restrict__ wk, const float* __restrict__ wv,
    float* __restrict__ ex, _Float16* __restrict__ wTh,
    _Float16* __restrict__ wTl) {
  int b = blockIdx.x;
  if (b >= 243) {  // transpose + hi/lo split part
    int i = (b - 243) * 256 + threadIdx.x;  // [0, 12288)
    int m = i >> 12;
    int r = i & 4095;
    int cp = r >> 6, c = r & 63;
    const float* src = (m == 0) ? wq : ((m == 1) ? wk : wv);
    float v = src[c * 64 + cp];
    _Float16 h = (_Float16)v;
    wTh[i] = h;
    wTl[i] = (_Float16)(v - (float)h);
    return;
  }
  int wi = b / 81;
  int pg = (b - wi * 81) * 256 + threadIdx.x;  // [0, NPOS)
  if (wi == 0)
    expand_body<2, 36>(x, exp_w, exp_b, ex, pg);
  else if (wi == 1)
    expand_body<4, 18>(x, exp_w + 4096, exp_b + 64, ex + (long)NPOS * 64, pg);
  else
    expand_body<6, 12>(x, exp_w + 8192, exp_b + 128, ex + 2L * NPOS * 64, pg);
}

// ---------------------------------------------------------------------------
// Kernel 2: q/k/v projections as MFMA fp16 hi/lo GEMM (3-term, fp32-equiv).
// Block = 64 tokens x 192 outs. Outputs in attention-ready split format:
//   qh/ql [tok][64] (pre-scaled by 0.125*log2e), kh/kl [tok][64],
//   vth/vtl group-transposed [win][g][ch][key].
// ---------------------------------------------------------------------------
__global__ __launch_bounds__(256) void k_qkv(
    const float* __restrict__ ex, const _Float16* __restrict__ wTh,
    const _Float16* __restrict__ wTl, _Float16* __restrict__ qh,
    _Float16* __restrict__ ql, _Float16* __restrict__ kh,
    _Float16* __restrict__ kl, _Float16* __restrict__ vth,
    _Float16* __restrict__ vtl) {
  __shared__ __align__(16) _Float16 Wh[12288], Wl[12288];  // 192x64 swizzled
  __shared__ __align__(16) float Cb[4096];  // bounce; overlays E staging
  _Float16* Eh = (_Float16*)Cb;             // [64][64] halves
  _Float16* El = (_Float16*)Cb + 4096;

  const int tid = threadIdx.x;
  const long tok0 = (long)blockIdx.x * 64;
  const int lane = tid & 63, w = tid >> 6;
  const int lw = lane & 15, lg = lane >> 4;

  // ---- stage E (split) ----
  {
    int srow = tid >> 2, sfq = tid & 3;
#pragma unroll
    for (int p = 0; p < 4; ++p) {
      int c0 = (4 * p + sfq) * 4;
      float4 v = *(const float4*)(ex + (tok0 + srow) * 64 + c0);
      h4 hh = {(_Float16)v.x, (_Float16)v.y, (_Float16)v.z, (_Float16)v.w};
      h4 ll = {(_Float16)(v.x - (float)hh[0]), (_Float16)(v.y - (float)hh[1]),
               (_Float16)(v.z - (float)hh[2]), (_Float16)(v.w - (float)hh[3])};
      *(h4*)&Eh[fidx(srow, c0 >> 3, c0 & 7)] = hh;
      *(h4*)&El[fidx(srow, c0 >> 3, c0 & 7)] = ll;
    }
  }
  // ---- stage W (straight split copies) ----
#pragma unroll
  for (int it = 0; it < 6; ++it) {
    int idx = it * 256 + tid;  // [0,1536) h8 index
    int row = idx >> 3, gr = idx & 7;
    *(h8*)&Wh[fidx(row, gr, 0)] = *(const h8*)(wTh + idx * 8);
    *(h8*)&Wl[fidx(row, gr, 0)] = *(const h8*)(wTl + idx * 8);
  }
  __syncthreads();

  // ---- A-fragments (E rows) to registers, then free the E region ----
  h8 eh[2], el[2];
#pragma unroll
  for (int s = 0; s < 2; ++s) {
    eh[s] = *(const h8*)&Eh[fidx(w * 16 + lw, s * 4 + lg, 0)];
    el[s] = *(const h8*)&El[fidx(w * 16 + lw, s * 4 + lg, 0)];
  }
  __syncthreads();

  const float SC = 0.125f * 1.4426950408889634f;
#pragma unroll 1
  for (int p = 0; p < 3; ++p) {
    // compute 4 out-tiles: C[tok= w*16+4lg+r][out= ot*16+lw]
#pragma unroll
    for (int ot = 0; ot < 4; ++ot) {
      f4 acc = (f4){0.f, 0.f, 0.f, 0.f};
#pragma unroll
      for (int s = 0; s < 2; ++s) {
        h8 bh = *(const h8*)&Wh[fidx(p * 64 + ot * 16 + lw, s * 4 + lg, 0)];
        h8 bl = *(const h8*)&Wl[fidx(p * 64 + ot * 16 + lw, s * 4 + lg, 0)];
        acc = __builtin_amdgcn_mfma_f32_16x16x32_f16(eh[s], bh, acc, 0, 0, 0);
        acc = __builtin_amdgcn_mfma_f32_16x16x32_f16(el[s], bh, acc, 0, 0, 0);
        acc = __builtin_amdgcn_mfma_f32_16x16x32_f16(eh[s], bl, acc, 0, 0, 0);
      }
#pragma unroll
      for (int r = 0; r < 4; ++r) {
        int row = w * 16 + 4 * lg + r;
        int col = ot * 16 + lw;
        Cb[(row << 6) + ((((col >> 2) ^ (row & 15))) << 2) + (col & 3)] =
            acc[r];
      }
    }
    __syncthreads();

    if (p < 2) {
      // q/k: token-major [tok][64] split store, coalesced h8 writes
      int tokl = tid >> 2, off = (tid & 3) * 16;
      float vals[16];
#pragma unroll
      for (int j = 0; j < 4; ++j) {
        int slot = (off >> 2) + j;
        f4 v = *(const f4*)&Cb[(tokl << 6) + (((slot ^ (tokl & 15))) << 2)];
        vals[4 * j + 0] = v[0]; vals[4 * j + 1] = v[1];
        vals[4 * j + 2] = v[2]; vals[4 * j + 3] = v[3];
      }
      float sc = (p == 0) ? SC : 1.0f;
      _Float16* dh = (p == 0 ? qh : kh) + (tok0 + tokl) * 64 + off;
      _Float16* dl = (p == 0 ? ql : kl) + (tok0 + tokl) * 64 + off;
      h8 hh0, hh1, ll0, ll1;
#pragma unroll
      for (int j = 0; j < 8; ++j) {
        float x0 = vals[j] * sc;
        _Float16 h = (_Float16)x0;
        hh0[j] = h;
        ll0[j] = (_Float16)(x0 - (float)h);
        float x1 = vals[8 + j] * sc;
        _Float16 h1 = (_Float16)x1;
        hh1[j] = h1;
        ll1[j] = (_Float16)(x1 - (float)h1);
      }
      *(h8*)dh = hh0; *(h8*)(dh + 8) = hh1;
      *(h8*)dl = ll0; *(h8*)(dl + 8) = ll1;
    } else {
      // v: group-transposed [win][g][ch][key] split store
      int ch0 = (tid & 15) * 4, tokl0 = (tid >> 4) * 4;
      float tv[4][4];
#pragma unroll
      for (int r = 0; r < 4; ++r) {
        int row = tokl0 + r;
        int slot = (ch0 >> 2) ^ (row & 15);
        f4 v = *(const f4*)&Cb[(row << 6) + (slot << 2)];
        tv[r][0] = v[0]; tv[r][1] = v[1]; tv[r][2] = v[2]; tv[r][3] = v[3];
      }
      long tokg = tok0 + tokl0;
      int wi = (int)(tokg / NPOS);
      long tl = tokg - (long)wi * NPOS;
      int L = (wi == 0) ? 1296 : ((wi == 1) ? 324 : 144);
      int g = (int)(tl / L);
      int key0 = (int)(tl - (long)g * L);
      long base = (long)wi * NPOS * 64 + (long)g * 64 * L + key0;
#pragma unroll
      for (int i = 0; i < 4; ++i) {
        h4 hh, ll;
#pragma unroll
        for (int r = 0; r < 4; ++r) {
          _Float16 h = (_Float16)tv[r][i];
          hh[r] = h;
          ll[r] = (_Float16)(tv[r][i] - (float)h);
        }
        *(h4*)&vth[base + (long)(ch0 + i) * L] = hh;
        *(h4*)&vtl[base + (long)(ch0 + i) * L] = ll;
      }
    }
    __syncthreads();
  }
}

// ---------------------------------------------------------------------------
// Kernel 3: merged MFMA attention; staging is pure h8 copies of presplit data.
// ---------------------------------------------------------------------------
__global__ __launch_bounds__(256) void k_attn(
    const _Float16* __restrict__ qg, const _Float16* __restrict__ qgl,
    const _Float16* __restrict__ kg, const _Float16* __restrict__ kgl,
    const _Float16* __restrict__ vg, const _Float16* __restrict__ vgl,
    float* __restrict__ og_) {
  __shared__ __align__(16) _Float16 Qh[4096], Ql[4096];
  __shared__ __align__(16) _Float16 Kh[4096], Kl[4096];
  __shared__ __align__(16) _Float16 Vh[4096], Vl[4096];  // V^T [ch][key]
  __shared__ __align__(16) _Float16 Ph[4096], Pl[4096];  // P  [q][key]

  const int tid = threadIdx.x;
  int b = blockIdx.x;
  int L, g, qt, NCH;
  long tokbase, vbase;
  if (b < 336) {
    L = 1296; NCH = 21; g = b / 21; qt = b - g * 21;
    tokbase = (long)g * 1296;
    vbase = (long)g * 64 * 1296;
  } else if (b < 720) {
    int t = b - 336;
    L = 324; NCH = 6; g = t / 6; qt = t - g * 6;
    tokbase = (long)NPOS + (long)g * 324;
    vbase = (long)NPOS * 64 + (long)g * 64 * 324;
  } else {
    int t = b - 720;
    L = 144; NCH = 3; g = t / 3; qt = t - g * 3;
    tokbase = 2L * NPOS + (long)g * 144;
    vbase = 2L * NPOS * 64 + (long)g * 64 * 144;
  }

  const int lane = tid & 63, w = tid >> 6;
  const int lw = lane & 15, lg = lane >> 4;
  const int w16 = w * 16;

  // ---- stage Q (straight swizzled copies; garbage tail is lane-contained)
#pragma unroll
  for (int it = 0; it < 2; ++it) {
    int idx = it * 256 + tid;
    int row = idx >> 3, gr = idx & 7;
    long src = (tokbase + qt * 64 + row) * 64 + gr * 8;
    *(h8*)&Qh[fidx(row, gr, 0)] = *(const h8*)(qg + src);
    *(h8*)&Ql[fidx(row, gr, 0)] = *(const h8*)(qgl + src);
  }

  float m_s = -1e30f, l_s = 0.f;
  f4 oa[4];
#pragma unroll
  for (int i = 0; i < 4; ++i) oa[i] = (f4){0.f, 0.f, 0.f, 0.f};

  h8 rk0, rk1, rl0, rl1, rv0, rv1, rw0, rw1;
  auto loadKV = [&](int chn) {
    {
      int idx = tid;
      int row = idx >> 3, gr = idx & 7;
      long ks = (tokbase + chn * 64 + row) * 64 + gr * 8;
      long vs = vbase + (long)row * L + chn * 64 + gr * 8;
      rk0 = *(const h8*)(kg + ks);
      rl0 = *(const h8*)(kgl + ks);
      rv0 = *(const h8*)(vg + vs);
      rw0 = *(const h8*)(vgl + vs);
    }
    {
      int idx = 256 + tid;
      int row = idx >> 3, gr = idx & 7;
      long ks = (tokbase + chn * 64 + row) * 64 + gr * 8;
      long vs = vbase + (long)row * L + chn * 64 + gr * 8;
      rk1 = *(const h8*)(kg + ks);
      rl1 = *(const h8*)(kgl + ks);
      rv1 = *(const h8*)(vg + vs);
      rw1 = *(const h8*)(vgl + vs);
    }
  };
  loadKV(0);

  for (int ch = 0; ch < NCH; ++ch) {
    __syncthreads();  // previous chunk's readers done
    {
      int row = tid >> 3, gr = tid & 7;
      *(h8*)&Kh[fidx(row, gr, 0)] = rk0;
      *(h8*)&Kl[fidx(row, gr, 0)] = rl0;
      *(h8*)&Vh[fidx(row, gr, 0)] = rv0;
      *(h8*)&Vl[fidx(row, gr, 0)] = rw0;
      int row1 = (256 + tid) >> 3;
      *(h8*)&Kh[fidx(row1, gr, 0)] = rk1;
      *(h8*)&Kl[fidx(row1, gr, 0)] = rl1;
      *(h8*)&Vh[fidx(row1, gr, 0)] = rv1;
      *(h8*)&Vl[fidx(row1, gr, 0)] = rw1;
    }
    __syncthreads();
    if (ch + 1 < NCH) loadKV(ch + 1);  // prefetch next chunk into regs

    // ---- S^T = K * Q^T ----
    f4 sa[4];
#pragma unroll
    for (int kt = 0; kt < 4; ++kt) sa[kt] = (f4){0.f, 0.f, 0.f, 0.f};
#pragma unroll
    for (int slab = 0; slab < 2; ++slab) {
      h8 qbh = *(const h8*)&Qh[fidx(w16 + lw, slab * 4 + lg, 0)];
      h8 qbl = *(const h8*)&Ql[fidx(w16 + lw, slab * 4 + lg, 0)];
#pragma unroll
      for (int kt = 0; kt < 4; ++kt) {
        h8 ah = *(const h8*)&Kh[fidx(kt * 16 + lw, slab * 4 + lg, 0)];
        h8 al = *(const h8*)&Kl[fidx(kt * 16 + lw, slab * 4 + lg, 0)];
        sa[kt] = __builtin_amdgcn_mfma_f32_16x16x32_f16(ah, qbh, sa[kt], 0, 0, 0);
        sa[kt] = __builtin_amdgcn_mfma_f32_16x16x32_f16(al, qbh, sa[kt], 0, 0, 0);
        sa[kt] = __builtin_amdgcn_mfma_f32_16x16x32_f16(ah, qbl, sa[kt], 0, 0, 0);
      }
    }

    // ---- online softmax (exp2 domain); 4 lanes (lg) share q = w16+lw ----
    float pr[4][4];
    float pmax = -1e30f;
#pragma unroll
    for (int kt = 0; kt < 4; ++kt)
#pragma unroll
      for (int r = 0; r < 4; ++r) {
        int kidx = ch * 64 + kt * 16 + 4 * lg + r;
        float s = (kidx < L) ? sa[kt][r] : -1e30f;
        pr[kt][r] = s;
        pmax = fmaxf(pmax, s);
      }
    pmax = fmaxf(pmax, __shfl_xor(pmax, 16));
    pmax = fmaxf(pmax, __shfl_xor(pmax, 32));
    float mn = fmaxf(m_s, pmax);
    float fs = exp2f(m_s - mn);
    m_s = mn;
    float rs = 0.f;
#pragma unroll
    for (int kt = 0; kt < 4; ++kt)
#pragma unroll
      for (int r = 0; r < 4; ++r) {
        float e = exp2f(pr[kt][r] - mn);
        pr[kt][r] = e;
        rs += e;
      }
    rs += __shfl_xor(rs, 16);
    rs += __shfl_xor(rs, 32);
    l_s = l_s * fs + rs;
    float fsb[4];
#pragma unroll
    for (int r = 0; r < 4; ++r) fsb[r] = __shfl(fs, 4 * lg + r);
#pragma unroll
    for (int ct = 0; ct < 4; ++ct)
#pragma unroll
      for (int r = 0; r < 4; ++r) oa[ct][r] *= fsb[r];

    // ---- store P [q][key] hi/lo (wave-private rows) ----
#pragma unroll
    for (int kt = 0; kt < 4; ++kt) {
      h4 hh = {(_Float16)pr[kt][0], (_Float16)pr[kt][1], (_Float16)pr[kt][2],
               (_Float16)pr[kt][3]};
      h4 ll = {(_Float16)(pr[kt][0] - (float)hh[0]),
               (_Float16)(pr[kt][1] - (float)hh[1]),
               (_Float16)(pr[kt][2] - (float)hh[2]),
               (_Float16)(pr[kt][3] - (float)hh[3])};
      int key0 = kt * 16 + 4 * lg;
      int kgr = key0 >> 3, ko = key0 & 7;
      *(h4*)&Ph[fidx(w16 + lw, kgr, ko)] = hh;
      *(h4*)&Pl[fidx(w16 + lw, kgr, ko)] = ll;
    }

    // ---- O += P * V ----
#pragma unroll
    for (int slab = 0; slab < 2; ++slab) {
      h8 pah = *(const h8*)&Ph[fidx(w16 + lw, slab * 4 + lg, 0)];
      h8 pal = *(const h8*)&Pl[fidx(w16 + lw, slab * 4 + lg, 0)];
#pragma unroll
      for (int ct = 0; ct < 4; ++ct) {
        h8 vbh = *(const h8*)&Vh[fidx(ct * 16 + lw, slab * 4 + lg, 0)];
        h8 vbl = *(const h8*)&Vl[fidx(ct * 16 + lw, slab * 4 + lg, 0)];
        oa[ct] = __builtin_amdgcn_mfma_f32_16x16x32_f16(pah, vbh, oa[ct], 0, 0, 0);
        oa[ct] = __builtin_amdgcn_mfma_f32_16x16x32_f16(pal, vbh, oa[ct], 0, 0, 0);
        oa[ct] = __builtin_amdgcn_mfma_f32_16x16x32_f16(pah, vbl, oa[ct], 0, 0, 0);
      }
    }
  }

  // ---- store O ----
  float linv[4];
#pragma unroll
  for (int r = 0; r < 4; ++r) linv[r] = 1.0f / __shfl(l_s, 4 * lg + r);
#pragma unroll
  for (int r = 0; r < 4; ++r) {
    int qi = qt * 64 + w16 + 4 * lg + r;
    if (qi < L) {
      float* op = og_ + (tokbase + qi) * 64 + lw;
#pragma unroll
      for (int ct = 0; ct < 4; ++ct) op[ct * 16] = oa[ct][r] * linv[r];
    }
  }
}

// ---------------------------------------------------------------------------
// Kernel 4: mask_fusion1 -> res conv -> mask_fusion2 -> fus conv.
// ---------------------------------------------------------------------------
__global__ __launch_bounds__(256) void k_fuse(
    const float* __restrict__ x, const float* __restrict__ ex,
    const float* __restrict__ att, const float* __restrict__ res_w,
    const float* __restrict__ res_b, const float* __restrict__ fus_w,
    const float* __restrict__ fus_b, const float* __restrict__ m1aw,
    const float* __restrict__ m1ab, const float* __restrict__ m1bw,
    const float* __restrict__ m1bb, const float* __restrict__ m2aw,
    const float* __restrict__ m2ab, const float* __restrict__ m2bw,
    const float* __restrict__ m2bb, float* __restrict__ out) {
  __shared__ float fT[192][68];
  const int tid = threadIdx.x;
  const int posb = blockIdx.x * 64;
  const int n = posb / HW;
  const int posn = posb % HW;

  {
    const int wv = tid >> 6, lane = tid & 63;
    float w1a0 = m1aw[0], w1a1 = m1aw[1], w1a2 = m1aw[2], w1a3 = m1aw[3];
    float b1a0 = m1ab[0], b1a1 = m1ab[1];
    float w1b0 = m1bw[0], w1b1 = m1bw[1], w1b2 = m1bw[2], w1b3 = m1bw[3];
    float b1b0 = m1bb[0], b1b1 = m1bb[1];
    for (int pp = 0; pp < 16; ++pp) {
      int pl = wv * 16 + pp;
      int pos = posn + pl;
      int h = pos / CW, wcol = pos % CW;
      auto tok = [&](int S, int W) -> int {
        int wr = h / S, kx = h % S, wcq = wcol / S, ky = wcol % S;
        return kx * (S * W * W) + ky * (W * W) + wr * W + wcq;
      };
      int j0 = tok(36, 2), j1 = tok(18, 4), j2 = tok(12, 6);
      long t0 = ((long)n * HW + j0) * 64 + lane;
      long t1 = ((long)NPOS + (long)n * HW + j1) * 64 + lane;
      long t2 = (2L * NPOS + (long)n * HW + j2) * 64 + lane;
      float av0 = att[t0], av1 = att[t1], av2 = att[t2];
      float ev0 = ex[t0], ev1 = ex[t1], ev2 = ex[t2];
      float mxa = fmaxf(fmaxf(av0, av1), av2), sma = av0 + av1 + av2;
      float mxe = fmaxf(fmaxf(ev0, ev1), ev2), sme = ev0 + ev1 + ev2;
#pragma unroll
      for (int d = 1; d < 64; d <<= 1) {
        mxa = fmaxf(mxa, __shfl_xor(mxa, d));
        sma += __shfl_xor(sma, d);
        mxe = fmaxf(mxe, __shfl_xor(mxe, d));
        sme += __shfl_xor(sme, d);
      }
      float mna = sma * (1.f / 192.f), mne = sme * (1.f / 192.f);
      float ca0 = fmaf(w1a0, mxa, fmaf(w1a1, mna, b1a0));
      float ca1 = fmaf(w1a2, mxa, fmaf(w1a3, mna, b1a1));
      float cb0 = fmaf(w1b0, mxe, fmaf(w1b1, mne, b1b0));
      float cb1 = fmaf(w1b2, mxe, fmaf(w1b3, mne, b1b1));
      bool mk = (ca0 * cb0 + ca1 * cb1) > 0.f;
      fT[lane][pl] = mk ? ev0 : av0;
      fT[64 + lane][pl] = mk ? ev1 : av1;
      fT[128 + lane][pl] = mk ? ev2 : av2;
    }
  }
  __syncthreads();

  const int ogi = tid & 15, pgi = tid >> 4;
  const int o4 = ogi * 4, p4 = pgi * 4;
  float acc[4][4];
#pragma unroll
  for (int i = 0; i < 4; ++i) {
    float b = res_b[o4 + i];
#pragma unroll
    for (int jj = 0; jj < 4; ++jj) acc[i][jj] = b;
  }
#pragma unroll 2
  for (int cg = 0; cg < 48; ++cg) {
    int cc = cg * 4;
    float wv4[4][4], fv4[4][4];
#pragma unroll
    for (int i = 0; i < 4; ++i) {
      float4 w4 = *(const float4*)(res_w + (o4 + i) * 192 + cc);
      wv4[i][0] = w4.x; wv4[i][1] = w4.y; wv4[i][2] = w4.z; wv4[i][3] = w4.w;
    }
#pragma unroll
    for (int u = 0; u < 4; ++u) {
      float4 f4_ = *(const float4*)&fT[cc + u][p4];
      fv4[u][0] = f4_.x; fv4[u][1] = f4_.y; fv4[u][2] = f4_.z; fv4[u][3] = f4_.w;
    }
#pragma unroll
    for (int i = 0; i < 4; ++i)
#pragma unroll
      for (int jj = 0; jj < 4; ++jj) {
        float a = acc[i][jj];
        a = fmaf(wv4[i][0], fv4[0][jj], a);
        a = fmaf(wv4[i][1], fv4[1][jj], a);
        a = fmaf(wv4[i][2], fv4[2][jj], a);
        a = fmaf(wv4[i][3], fv4[3][jj], a);
        acc[i][jj] = a;
      }
  }

  float rmx[4], rsm[4];
#pragma unroll
  for (int jj = 0; jj < 4; ++jj) {
    rmx[jj] = fmaxf(fmaxf(acc[0][jj], acc[1][jj]), fmaxf(acc[2][jj], acc[3][jj]));
    rsm[jj] = acc[0][jj] + acc[1][jj] + acc[2][jj] + acc[3][jj];
  }
#pragma unroll
  for (int d = 1; d < 16; d <<= 1)
#pragma unroll
    for (int jj = 0; jj < 4; ++jj) {
      rmx[jj] = fmaxf(rmx[jj], __shfl_xor(rmx[jj], d));
      rsm[jj] += __shfl_xor(rsm[jj], d);
    }
  const float* xp = x + (long)n * CC * HW + posn;
  float xv[4][4];
#pragma unroll
  for (int i = 0; i < 4; ++i)
#pragma unroll
    for (int jj = 0; jj < 4; ++jj)
      xv[i][jj] = xp[(o4 + i) * HW + p4 + jj];
  float xmx[4], xsm[4];
#pragma unroll
  for (int jj = 0; jj < 4; ++jj) {
    xmx[jj] = fmaxf(fmaxf(xv[0][jj], xv[1][jj]), fmaxf(xv[2][jj], xv[3][jj]));
    xsm[jj] = xv[0][jj] + xv[1][jj] + xv[2][jj] + xv[3][jj];
  }
#pragma unroll
  for (int d = 1; d < 16; d <<= 1)
#pragma unroll
    for (int jj = 0; jj < 4; ++jj) {
      xmx[jj] = fmaxf(xmx[jj], __shfl_xor(xmx[jj], d));
      xsm[jj] += __shfl_xor(xsm[jj], d);
    }
  float w2a0 = m2aw[0], w2a1 = m2aw[1], w2a2 = m2aw[2], w2a3 = m2aw[3];
  float b2a0 = m2ab[0], b2a1 = m2ab[1];
  float w2b0 = m2bw[0], w2b1 = m2bw[1], w2b2 = m2bw[2], w2b3 = m2bw[3];
  float b2b0 = m2bb[0], b2b1 = m2bb[1];
  bool mk2[4];
#pragma unroll
  for (int jj = 0; jj < 4; ++jj) {
    float rmn = rsm[jj] * (1.f / 64.f), xmn = xsm[jj] * (1.f / 64.f);
    float ca0 = fmaf(w2a0, rmx[jj], fmaf(w2a1, rmn, b2a0));
    float ca1 = fmaf(w2a2, rmx[jj], fmaf(w2a3, rmn, b2a1));
    float cb0 = fmaf(w2b0, xmx[jj], fmaf(w2b1, xmn, b2b0));
    float cb1 = fmaf(w2b2, xmx[jj], fmaf(w2b3, xmn, b2b1));
    mk2[jj] = (ca0 * cb0 + ca1 * cb1) > 0.f;
  }
  __syncthreads();
#pragma unroll
  for (int i = 0; i < 4; ++i)
#pragma unroll
    for (int jj = 0; jj < 4; ++jj)
      fT[o4 + i][p4 + jj] = mk2[jj] ? xv[i][jj] : acc[i][jj];
  __syncthreads();

  float a2[4][4];
#pragma unroll
  for (int i = 0; i < 4; ++i) {
    float b = fus_b[o4 + i];
#pragma unroll
    for (int jj = 0; jj < 4; ++jj) a2[i][jj] = b;
  }
#pragma unroll 2
  for (int cg = 0; cg < 16; ++cg) {
    int cc = cg * 4;
    float wv4[4][4], fv4[4][4];
#pragma unroll
    for (int i = 0; i < 4; ++i) {
      float4 w4 = *(const float4*)(fus_w + (o4 + i) * 64 + cc);
      wv4[i][0] = w4.x; wv4[i][1] = w4.y; wv4[i][2] = w4.z; wv4[i][3] = w4.w;
    }
#pragma unroll
    for (int u = 0; u < 4; ++u) {
      float4 f4_ = *(const float4*)&fT[cc + u][p4];
      fv4[u][0] = f4_.x; fv4[u][1] = f4_.y; fv4[u][2] = f4_.z; fv4[u][3] = f4_.w;
    }
#pragma unroll
    for (int i = 0; i < 4; ++i)
#pragma unroll
      for (int jj = 0; jj < 4; ++jj) {
        float a = a2[i][jj];
        a = fmaf(wv4[i][0], fv4[0][jj], a);
        a = fmaf(wv4[i][1], fv4[1][jj], a);
        a = fmaf(wv4[i][2], fv4[2][jj], a);
        a = fmaf(wv4[i][3], fv4[3][jj], a);
        a2[i][jj] = a;
      }
  }
#pragma unroll
  for (int i = 0; i < 4; ++i)
    *(float4*)(out + ((long)n * CC + o4 + i) * HW + posn + p4) =
        make_float4(a2[i][0], a2[i][1], a2[i][2], a2[i][3]);
}

// ---------------------------------------------------------------------------
extern "C" void kernel_launch(void* const* d_in, const int* in_sizes, int n_in,
                              void* d_out, int out_size, void* d_ws,
                              size_t ws_size, hipStream_t stream) {
  (void)in_sizes; (void)n_in; (void)out_size;
  const float* x      = (const float*)d_in[0];
  const float* exp_w  = (const float*)d_in[1];
  const float* exp_b  = (const float*)d_in[2];
  const float* res_w  = (const float*)d_in[3];
  const float* res_b  = (const float*)d_in[4];
  const float* fus_w  = (const float*)d_in[5];
  const float* fus_b  = (const float*)d_in[6];
  const float* wq     = (const float*)d_in[7];
  const float* wk     = (const float*)d_in[8];
  const float* wv     = (const float*)d_in[9];
  const float* m1aw   = (const float*)d_in[10];
  const float* m1ab   = (const float*)d_in[11];
  const float* m1bw   = (const float*)d_in[12];
  const float* m1bb   = (const float*)d_in[13];
  const float* m2aw   = (const float*)d_in[14];
  const float* m2ab   = (const float*)d_in[15];
  const float* m2bw   = (const float*)d_in[16];
  const float* m2bb   = (const float*)d_in[17];

  const long HSZ = TOKF + HPAD;  // halves per padded half-array
  const size_t needF = 2 * (size_t)TOKF + (6 * (size_t)HSZ + 2 * 12288) / 2;
  if (ws_size < needF * sizeof(float)) return;
  float* ws = (float*)d_ws;
  float* ex = ws;                              // TOKF f32
  float* ob = ex + TOKF;                       // TOKF f32
  _Float16* qh  = (_Float16*)(ob + TOKF);
  _Float16* ql  = qh + HSZ;
  _Float16* kh  = ql + HSZ;
  _Float16* kl  = kh + HSZ;
  _Float16* vth = kl + HSZ;
  _Float16* vtl = vth + HSZ;
  _Float16* wTh = vtl + HSZ;                   // 12288 halves
  _Float16* wTl = wTh + 12288;

  k_prep<<<291, 256, 0, stream>>>(x, exp_w, exp_b, wq, wk, wv, ex, wTh, wTl);
  k_qkv<<<972, 256, 0, stream>>>(ex, wTh, wTl, qh, ql, kh, kl, vth, vtl);
  k_attn<<<1152, 256, 0, stream>>>(qh, ql, kh, kl, vth, vtl, ob);
  k_fuse<<<324, 256, 0, stream>>>(x, ex, ob, res_w, res_b, fus_w, fus_b, m1aw,
                                  m1ab, m1bw, m1bb, m2aw, m2ab, m2bw, m2bb,
                                  (float*)d_out);
}